// Round 1
// baseline (1315.358 us; speedup 1.0000x reference)
//
#include <hip/hip_runtime.h>
#include <float.h>

// ---------------------------------------------------------------------------
// Fused dual-attention (SCA + SSA), all-fp32 correctness-first implementation.
//
//  SEQ=1024, B=8, E=512, H=8, HD=64.  T1=0.6 (SCA), T2=0.4 (SSA).
//
//  Pipeline:
//   1. proj_gemm x3: Qsem=q_sem@Wq, Ksem=k_sem@Wk, V=v@Wv   (head layout [bh][t][d])
//   2. sca_kernel: masked softmax attention (no max-sub needed; |score|<~20),
//      writes T1*o_sca into MIX[t*8+b][h*64+d]
//   3. proj_gemm x2: Q=q@Wq, K=k@Wk  (reusing the Qsem/Ksem buffers)
//   4. ssa_kernel: masked argmax (fp32-exact — discrete decision!), adds
//      T2*v[argmax] into MIX
//   5. proj_gemm: out = MIX@Wo^T + bo  (T1+T2 = 1 so bias scale is exactly 1)
// ---------------------------------------------------------------------------

namespace {
constexpr int kSeq = 1024;
constexpr int kBsz = 8;
constexpr int kEmb = 512;
constexpr int kHD  = 64;
constexpr float kT1 = 0.6f;
constexpr float kT2 = 0.4f;
constexpr float kScale = 0.125f;   // 1/sqrt(64)
}

// Chunk-rotation swizzle for 64-float rows (16 float4 chunks), stride-68 LDS.
// Rows that differ in bits 4..5 (the 4 broadcast rows per wave) get distinct
// bank quads; without this, stride*16 = 0 mod 32 -> 4-way conflict per read.
__device__ __forceinline__ int swz(int row, int chunk) {
  return ((chunk + (row >> 4)) & 15) << 2;
}

// out[m,n] = sum_k X[m,k] * W[woff+n,k] + bias[woff+n]
// headLayout: Out[((m&7)*8 + n/64)][m>>3][n&63]  (i.e. [bh][t][d]); else Out[m][n].
__global__ __launch_bounds__(256, 4) void proj_gemm(
    const float* __restrict__ X, const float* __restrict__ W,
    const float* __restrict__ bias, float* __restrict__ Out,
    int woff, int headLayout)
{
  __shared__ float As[16][68];   // [k][m], padded
  __shared__ float Bs[16][68];   // [k][n]
  const int mBase = blockIdx.x << 6;
  const int nBase = blockIdx.y << 6;
  const int tid = threadIdx.x;
  const int tx = tid & 15, ty = tid >> 4;
  const int sr = tid >> 2;            // staging row 0..63
  const int sk = (tid & 3) << 2;      // staging k 0,4,8,12
  const float* xp = X + (mBase + sr) * kEmb + sk;
  const float* wp = W + (woff + nBase + sr) * kEmb + sk;

  float acc[4][4];
#pragma unroll
  for (int i = 0; i < 4; ++i)
#pragma unroll
    for (int j = 0; j < 4; ++j) acc[i][j] = 0.f;

  for (int k0 = 0; k0 < kEmb; k0 += 16) {
    float4 a = *(const float4*)(xp + k0);
    float4 b = *(const float4*)(wp + k0);
    __syncthreads();
    As[sk + 0][sr] = a.x; As[sk + 1][sr] = a.y; As[sk + 2][sr] = a.z; As[sk + 3][sr] = a.w;
    Bs[sk + 0][sr] = b.x; Bs[sk + 1][sr] = b.y; Bs[sk + 2][sr] = b.z; Bs[sk + 3][sr] = b.w;
    __syncthreads();
#pragma unroll
    for (int k = 0; k < 16; ++k) {
      float4 av = *(const float4*)&As[k][ty << 2];
      float4 bv = *(const float4*)&Bs[k][tx << 2];
      float aa[4] = {av.x, av.y, av.z, av.w};
      float bb[4] = {bv.x, bv.y, bv.z, bv.w};
#pragma unroll
      for (int i = 0; i < 4; ++i)
#pragma unroll
        for (int j = 0; j < 4; ++j)
          acc[i][j] = fmaf(aa[i], bb[j], acc[i][j]);
    }
  }
#pragma unroll
  for (int i = 0; i < 4; ++i) {
    const int m = mBase + (ty << 2) + i;
#pragma unroll
    for (int j = 0; j < 4; ++j) {
      const int n = nBase + (tx << 2) + j;
      const float v = acc[i][j] + bias[woff + n];
      if (headLayout) {
        Out[(((m & 7) << 3) + (n >> 6)) * (kSeq * kHD) + ((m >> 3) << 6) + (n & 63)] = v;
      } else {
        Out[m * kEmb + n] = v;
      }
    }
  }
}

// SCA: block = (bh, 64 t-rows). Thread (r,c): row r, s-subset c*16..c*16+15
// per 64-tile. q row in VGPRs, k/v staged in LDS (swizzled), sem from global.
// Accumulates num[64]/den per thread, 4-way cross-c reduce at the end.
__global__ __launch_bounds__(256, 2) void sca_kernel(
    const float* __restrict__ Q, const float* __restrict__ K,
    const float* __restrict__ V, const float* __restrict__ SEM,
    float* __restrict__ MIX)
{
  __shared__ float ks[64][68];
  __shared__ float vs[64][68];
  __shared__ float red[64][68];
  __shared__ float dred[64][4];

  const int bh = blockIdx.x;
  const int tBase = blockIdx.y << 6;
  const int tid = threadIdx.x;
  const int r = tid >> 2;
  const int c = tid & 3;

  float4 qreg[16];
  {
    const float* qrow = Q + bh * (kSeq * kHD) + (tBase + r) * kHD;
#pragma unroll
    for (int i = 0; i < 16; ++i) {
      float4 t = *(const float4*)(qrow + (i << 2));
      qreg[i] = make_float4(t.x * kScale, t.y * kScale, t.z * kScale, t.w * kScale);
    }
  }
  float4 num[16];
#pragma unroll
  for (int i = 0; i < 16; ++i) num[i] = make_float4(0.f, 0.f, 0.f, 0.f);
  float den = 0.f;

  const float* semrow = SEM + (tBase + r) * kSeq + (c << 4);

  for (int s0 = 0; s0 < kSeq; s0 += 64) {
    __syncthreads();
    {
      const float* kb = K + bh * (kSeq * kHD) + s0 * kHD;
      const float* vb = V + bh * (kSeq * kHD) + s0 * kHD;
#pragma unroll
      for (int i = 0; i < 4; ++i) {
        int f = (i << 8) + tid;        // 1024 float4s
        int row = f >> 4, ch = f & 15;
        float4 kv = *(const float4*)(kb + (row << 6) + (ch << 2));
        float4 vv = *(const float4*)(vb + (row << 6) + (ch << 2));
        *(float4*)&ks[row][swz(row, ch)] = kv;
        *(float4*)&vs[row][swz(row, ch)] = vv;
      }
    }
    __syncthreads();

#pragma unroll 4
    for (int j = 0; j < 16; ++j) {
      const int sl = (c << 4) + j;
      float p0 = 0.f, p1 = 0.f, p2 = 0.f, p3 = 0.f;
#pragma unroll
      for (int i = 0; i < 16; ++i) {
        float4 kk = *(const float4*)&ks[sl][swz(sl, i)];
        p0 = fmaf(qreg[i].x, kk.x, p0);
        p1 = fmaf(qreg[i].y, kk.y, p1);
        p2 = fmaf(qreg[i].z, kk.z, p2);
        p3 = fmaf(qreg[i].w, kk.w, p3);
      }
      const float sc = (p0 + p1) + (p2 + p3);
      const float msk = semrow[s0 + j];
      const float w = (msk < 0.5f) ? 0.f : __expf(sc);
      den += w;
#pragma unroll
      for (int i = 0; i < 16; ++i) {
        float4 vv = *(const float4*)&vs[sl][swz(sl, i)];
        num[i].x = fmaf(w, vv.x, num[i].x);
        num[i].y = fmaf(w, vv.y, num[i].y);
        num[i].z = fmaf(w, vv.z, num[i].z);
        num[i].w = fmaf(w, vv.w, num[i].w);
      }
    }
  }

  dred[r][c] = den;
#pragma unroll 1
  for (int cc = 1; cc < 4; ++cc) {
    __syncthreads();
    if (c == cc) {
#pragma unroll
      for (int i = 0; i < 16; ++i) *(float4*)&red[r][i << 2] = num[i];
    }
    __syncthreads();
    if (c == 0) {
#pragma unroll
      for (int i = 0; i < 16; ++i) {
        float4 t = *(const float4*)&red[r][i << 2];
        num[i].x += t.x; num[i].y += t.y; num[i].z += t.z; num[i].w += t.w;
      }
    }
  }
  if (c == 0) {
    const float dsum = dred[r][0] + dred[r][1] + dred[r][2] + dred[r][3];
    const float sc = kT1 / dsum;
    const int t = tBase + r;
    const int b = bh >> 3, h = bh & 7;
    float* op = MIX + (t * kBsz + b) * kEmb + (h << 6);
#pragma unroll
    for (int i = 0; i < 16; ++i) {
      *(float4*)(op + (i << 2)) =
          make_float4(num[i].x * sc, num[i].y * sc, num[i].z * sc, num[i].w * sc);
    }
  }
}

// SSA: masked argmax per row (fp32 exact), then MIX += T2 * v[argmax].
// Tie-break: first (smallest) index, matching jnp.argmax.
__global__ __launch_bounds__(256, 4) void ssa_kernel(
    const float* __restrict__ Q, const float* __restrict__ K,
    const float* __restrict__ V, const float* __restrict__ SEM,
    float* __restrict__ MIX)
{
  __shared__ float ks[64][68];
  __shared__ float rv[64][4];
  __shared__ int   ri[64][4];
  __shared__ int   rowIdx[64];

  const int bh = blockIdx.x;
  const int tBase = blockIdx.y << 6;
  const int tid = threadIdx.x;
  const int r = tid >> 2;
  const int c = tid & 3;

  float4 qreg[16];
  {
    const float* qrow = Q + bh * (kSeq * kHD) + (tBase + r) * kHD;
#pragma unroll
    for (int i = 0; i < 16; ++i) {
      float4 t = *(const float4*)(qrow + (i << 2));
      qreg[i] = make_float4(t.x * kScale, t.y * kScale, t.z * kScale, t.w * kScale);
    }
  }
  float best = -FLT_MAX;
  int bidx = 0;
  const float* semrow = SEM + (tBase + r) * kSeq + (c << 4);

  for (int s0 = 0; s0 < kSeq; s0 += 64) {
    __syncthreads();
    {
      const float* kb = K + bh * (kSeq * kHD) + s0 * kHD;
#pragma unroll
      for (int i = 0; i < 4; ++i) {
        int f = (i << 8) + tid;
        int row = f >> 4, ch = f & 15;
        *(float4*)&ks[row][swz(row, ch)] = *(const float4*)(kb + (row << 6) + (ch << 2));
      }
    }
    __syncthreads();

#pragma unroll 4
    for (int j = 0; j < 16; ++j) {
      const int sl = (c << 4) + j;
      float p0 = 0.f, p1 = 0.f, p2 = 0.f, p3 = 0.f;
#pragma unroll
      for (int i = 0; i < 16; ++i) {
        float4 kk = *(const float4*)&ks[sl][swz(sl, i)];
        p0 = fmaf(qreg[i].x, kk.x, p0);
        p1 = fmaf(qreg[i].y, kk.y, p1);
        p2 = fmaf(qreg[i].z, kk.z, p2);
        p3 = fmaf(qreg[i].w, kk.w, p3);
      }
      const float sc = (p0 + p1) + (p2 + p3);
      const float msk = semrow[s0 + j];
      if (msk >= 0.5f && sc > best) { best = sc; bidx = s0 + sl; }
    }
  }
  rv[r][c] = best;
  ri[r][c] = bidx;
  __syncthreads();
  if (tid < 64) {
    float bb = rv[tid][0];
    int ii = ri[tid][0];
#pragma unroll
    for (int cc = 1; cc < 4; ++cc) {
      float v2 = rv[tid][cc];
      int i2 = ri[tid][cc];
      if (v2 > bb || (v2 == bb && i2 < ii)) { bb = v2; ii = i2; }
    }
    rowIdx[tid] = ii;
  }
  __syncthreads();
  {
    const int s = rowIdx[r];
    const float* vrow = V + bh * (kSeq * kHD) + s * kHD + (c << 4);
    const int t = tBase + r, b = bh >> 3, h = bh & 7;
    float* op = MIX + (t * kBsz + b) * kEmb + (h << 6) + (c << 4);
#pragma unroll
    for (int i = 0; i < 4; ++i) {
      float4 vv = *(const float4*)(vrow + (i << 2));
      float4 o = *(float4*)(op + (i << 2));
      o.x = fmaf(kT2, vv.x, o.x);
      o.y = fmaf(kT2, vv.y, o.y);
      o.z = fmaf(kT2, vv.z, o.z);
      o.w = fmaf(kT2, vv.w, o.w);
      *(float4*)(op + (i << 2)) = o;
    }
  }
}

extern "C" void kernel_launch(void* const* d_in, const int* in_sizes, int n_in,
                              void* d_out, int out_size, void* d_ws, size_t ws_size,
                              hipStream_t stream) {
  const float* query  = (const float*)d_in[0];
  const float* key    = (const float*)d_in[1];
  const float* value  = (const float*)d_in[2];
  const float* qsem   = (const float*)d_in[3];
  const float* ksem   = (const float*)d_in[4];
  const float* semmap = (const float*)d_in[5];
  const float* Wi     = (const float*)d_in[6];
  const float* bi     = (const float*)d_in[7];
  const float* Wo     = (const float*)d_in[8];
  const float* bo     = (const float*)d_in[9];
  float* out = (float*)d_out;

  const size_t kProjElems = (size_t)64 * kSeq * kHD;  // 4,194,304
  float* P0  = (float*)d_ws;
  float* P1  = P0 + kProjElems;
  float* P2  = P1 + kProjElems;
  float* MIX = P2 + kProjElems;

  const dim3 gg(128, 8);     // 8192/64 x 512/64
  const dim3 ga(64, 16);     // bh x t-tiles

  // SCA projections
  proj_gemm<<<gg, 256, 0, stream>>>(qsem,  Wi, bi, P0, 0,    1);
  proj_gemm<<<gg, 256, 0, stream>>>(ksem,  Wi, bi, P1, 512,  1);
  proj_gemm<<<gg, 256, 0, stream>>>(value, Wi, bi, P2, 1024, 1);
  // SCA attention -> MIX = T1 * o_sca
  sca_kernel<<<ga, 256, 0, stream>>>(P0, P1, P2, semmap, MIX);
  // SSA projections (reuse P0/P1)
  proj_gemm<<<gg, 256, 0, stream>>>(query, Wi, bi, P0, 0,    1);
  proj_gemm<<<gg, 256, 0, stream>>>(key,   Wi, bi, P1, 512,  1);
  // SSA argmax-gather -> MIX += T2 * v[argmax]
  ssa_kernel<<<ga, 256, 0, stream>>>(P0, P1, P2, semmap, MIX);
  // Shared out-projection
  proj_gemm<<<gg, 256, 0, stream>>>(MIX, Wo, bo, out, 0, 0);
}

// Round 2
// 822.069 us; speedup vs baseline: 1.6001x; 1.6001x over previous
//
#include <hip/hip_runtime.h>
#include <float.h>

// ---------------------------------------------------------------------------
// Fused dual-attention (SCA + SSA).  SEQ=1024, B=8, E=512, H=8, HD=64.
//
//  R2 change: sca_kernel (609us, LDS-issue-bound fp32 VALU) replaced by
//  sca_mfma: bf16 MFMA 16x16x32 flash-style attention, fp32 accumulate.
//  SCA is soft (softmax) -> bf16 q/k/v rounding is ~4e-3 at the output.
//  SSA path stays fp32 (argmax is a discrete decision; bf16 would flip it).
// ---------------------------------------------------------------------------

namespace {
constexpr int kSeq = 1024;
constexpr int kBsz = 8;
constexpr int kEmb = 512;
constexpr int kHD  = 64;
constexpr float kT1 = 0.6f;
constexpr float kT2 = 0.4f;
constexpr float kScale = 0.125f;   // 1/sqrt(64)
}

typedef short bf16x8 __attribute__((ext_vector_type(8)));
typedef float f32x4  __attribute__((ext_vector_type(4)));

union FragU { uint4 u4; bf16x8 f; };

__device__ __forceinline__ ushort f2bf(float f) {
  uint u = __float_as_uint(f);
  u += 0x7fff + ((u >> 16) & 1);        // RNE
  return (ushort)(u >> 16);
}
__device__ __forceinline__ uint pack2(float lo, float hi) {
  return (uint)f2bf(lo) | ((uint)f2bf(hi) << 16);
}

// Chunk-rotation swizzle used by the fp32 ssa path (unchanged from R1).
__device__ __forceinline__ int swz(int row, int chunk) {
  return ((chunk + (row >> 4)) & 15) << 2;
}

// out[m,n] = sum_k X[m,k] * W[woff+n,k] + bias[woff+n]
__global__ __launch_bounds__(256, 4) void proj_gemm(
    const float* __restrict__ X, const float* __restrict__ W,
    const float* __restrict__ bias, float* __restrict__ Out,
    int woff, int headLayout)
{
  __shared__ float As[16][68];
  __shared__ float Bs[16][68];
  const int mBase = blockIdx.x << 6;
  const int nBase = blockIdx.y << 6;
  const int tid = threadIdx.x;
  const int tx = tid & 15, ty = tid >> 4;
  const int sr = tid >> 2;
  const int sk = (tid & 3) << 2;
  const float* xp = X + (mBase + sr) * kEmb + sk;
  const float* wp = W + (woff + nBase + sr) * kEmb + sk;

  float acc[4][4];
#pragma unroll
  for (int i = 0; i < 4; ++i)
#pragma unroll
    for (int j = 0; j < 4; ++j) acc[i][j] = 0.f;

  for (int k0 = 0; k0 < kEmb; k0 += 16) {
    float4 a = *(const float4*)(xp + k0);
    float4 b = *(const float4*)(wp + k0);
    __syncthreads();
    As[sk + 0][sr] = a.x; As[sk + 1][sr] = a.y; As[sk + 2][sr] = a.z; As[sk + 3][sr] = a.w;
    Bs[sk + 0][sr] = b.x; Bs[sk + 1][sr] = b.y; Bs[sk + 2][sr] = b.z; Bs[sk + 3][sr] = b.w;
    __syncthreads();
#pragma unroll
    for (int k = 0; k < 16; ++k) {
      float4 av = *(const float4*)&As[k][ty << 2];
      float4 bv = *(const float4*)&Bs[k][tx << 2];
      float aa[4] = {av.x, av.y, av.z, av.w};
      float bb[4] = {bv.x, bv.y, bv.z, bv.w};
#pragma unroll
      for (int i = 0; i < 4; ++i)
#pragma unroll
        for (int j = 0; j < 4; ++j)
          acc[i][j] = fmaf(aa[i], bb[j], acc[i][j]);
    }
  }
#pragma unroll
  for (int i = 0; i < 4; ++i) {
    const int m = mBase + (ty << 2) + i;
#pragma unroll
    for (int j = 0; j < 4; ++j) {
      const int n = nBase + (tx << 2) + j;
      const float v = acc[i][j] + bias[woff + n];
      if (headLayout) {
        Out[(((m & 7) << 3) + (n >> 6)) * (kSeq * kHD) + ((m >> 3) << 6) + (n & 63)] = v;
      } else {
        Out[m * kEmb + n] = v;
      }
    }
  }
}

// ---------------------------------------------------------------------------
// SCA via MFMA.  Block = (t-tile of 64 rows, bh).  4 waves; wave w owns rows
// [w*16, w*16+16).  Loop over 64-wide s-tiles:
//   S = Q K^T (2 chained 16x16x32 MFMA per 16-col subtile),
//   mask+exp in C-layout, den[] accumulated per row,
//   P -> per-wave LDS (C-layout write / A-layout b128 read, rotation-swizzled),
//   O += P V (V staged transposed [d][s-pairs], rotation-swizzled).
// Layout facts used (guide §3, m89/m91/m120 verified):
//   C/D: col=lane&15, row=quad*4+reg.   A: [m=lane&15][k=quad*8+j].
//   B:   [k=quad*8+j][n=lane&15].
// ---------------------------------------------------------------------------
__global__ __launch_bounds__(256, 4) void sca_mfma(
    const float* __restrict__ Q, const float* __restrict__ K,
    const float* __restrict__ V, const float* __restrict__ SEM,
    float* __restrict__ MIX)
{
  __shared__ uint ks[64 * 36];     // K tile  [s][d/2], stride 36 words
  __shared__ uint vt[64 * 36];     // V^T tile [d][s/2 rotated], stride 36
  __shared__ uint ps[4][16 * 36];  // per-wave P tile [t][s/2 rotated]

  const int t0  = blockIdx.x << 6;
  const int bh  = blockIdx.y;
  const int tid = threadIdx.x;
  const int w    = tid >> 6;
  const int l    = tid & 63;
  const int l15  = l & 15;
  const int quad = l >> 4;

  const float* Qb = Q + bh * (kSeq * kHD);
  const float* Kb = K + bh * (kSeq * kHD);
  const float* Vb = V + bh * (kSeq * kHD);

  // Q fragments (1/sqrt(64) folded in).  qf0: d=quad*8+j; qf1: d=32+quad*8+j.
  FragU qf0, qf1;
  {
    const float* qrow = Qb + (t0 + (w << 4) + l15) * kHD + (quad << 3);
    float4 a = *(const float4*)qrow;
    float4 b = *(const float4*)(qrow + 4);
    float4 c = *(const float4*)(qrow + 32);
    float4 d = *(const float4*)(qrow + 36);
    qf0.u4 = make_uint4(pack2(a.x * kScale, a.y * kScale), pack2(a.z * kScale, a.w * kScale),
                        pack2(b.x * kScale, b.y * kScale), pack2(b.z * kScale, b.w * kScale));
    qf1.u4 = make_uint4(pack2(c.x * kScale, c.y * kScale), pack2(c.z * kScale, c.w * kScale),
                        pack2(d.x * kScale, d.y * kScale), pack2(d.z * kScale, d.w * kScale));
  }

  f32x4 oacc[4];
#pragma unroll
  for (int nt = 0; nt < 4; ++nt) oacc[nt] = (f32x4){0.f, 0.f, 0.f, 0.f};
  float den[4] = {0.f, 0.f, 0.f, 0.f};

  uint* psw = ps[w];

  for (int s0 = 0; s0 < kSeq; s0 += 64) {
    __syncthreads();
    // ---- stage K tile: thread covers row s=tid>>2, d-chunk (tid&3)*16 ----
    {
      const int sl = tid >> 2, c = tid & 3;
      const float* kp = Kb + (s0 + sl) * kHD + (c << 4);
      float4 k0 = ((const float4*)kp)[0];
      float4 k1 = ((const float4*)kp)[1];
      float4 k2 = ((const float4*)kp)[2];
      float4 k3 = ((const float4*)kp)[3];
      uint* dst = ks + sl * 36 + (c << 3);
      ((uint2*)dst)[0] = make_uint2(pack2(k0.x, k0.y), pack2(k0.z, k0.w));
      ((uint2*)dst)[1] = make_uint2(pack2(k1.x, k1.y), pack2(k1.z, k1.w));
      ((uint2*)dst)[2] = make_uint2(pack2(k2.x, k2.y), pack2(k2.z, k2.w));
      ((uint2*)dst)[3] = make_uint2(pack2(k3.x, k3.y), pack2(k3.z, k3.w));
    }
    // ---- stage V^T: thread covers s-pair p=tid>>3, d-chunk (tid&7)*8 ----
    {
      const int p = tid >> 3, c7 = tid & 7;
      const float* va = Vb + (s0 + (p << 1)) * kHD + (c7 << 3);
      float4 a0 = ((const float4*)va)[0];
      float4 a1 = ((const float4*)va)[1];
      float4 b0 = ((const float4*)(va + kHD))[0];
      float4 b1 = ((const float4*)(va + kHD))[1];
      const int Wp = (p + ((c7 & 3) << 2)) & 31;   // rotation kills the 8-way
      float av[8] = {a0.x, a0.y, a0.z, a0.w, a1.x, a1.y, a1.z, a1.w};
      float bv[8] = {b0.x, b0.y, b0.z, b0.w, b1.x, b1.y, b1.z, b1.w};
#pragma unroll
      for (int i = 0; i < 8; ++i)
        vt[((c7 << 3) + i) * 36 + Wp] = pack2(av[i], bv[i]);
    }
    __syncthreads();

    // ---- S = Q K^T, mask, exp, P write (per wave, no cross-wave dep) ----
#pragma unroll
    for (int st = 0; st < 4; ++st) {
      f32x4 sacc = (f32x4){0.f, 0.f, 0.f, 0.f};
      const int srow = (st << 4) + l15;
      FragU kf0, kf1;
      kf0.u4 = *(const uint4*)(ks + srow * 36 + (quad << 2));
      kf1.u4 = *(const uint4*)(ks + srow * 36 + 16 + (quad << 2));
      sacc = __builtin_amdgcn_mfma_f32_16x16x32_bf16(qf0.f, kf0.f, sacc, 0, 0, 0);
      sacc = __builtin_amdgcn_mfma_f32_16x16x32_bf16(qf1.f, kf1.f, sacc, 0, 0, 0);

      const int sg = s0 + (st << 4) + l15;
#pragma unroll
      for (int r = 0; r < 4; ++r) {
        const int trow = (quad << 2) + r;
        const float sem = SEM[(t0 + (w << 4) + trow) * kSeq + sg];
        const float val = (sem < 0.5f) ? 0.f : __expf(sacc[r]);
        den[r] += val;
        const int W  = (st << 3) + (l15 >> 1);
        const int Wp = (W + (((trow >> 3) & 1) << 3)) & 31;  // row-rotation
        ushort* p16 = (ushort*)(psw + trow * 36 + Wp);
        p16[l15 & 1] = f2bf(val);
      }
    }
    // ---- O += P V ----
#pragma unroll
    for (int ch = 0; ch < 2; ++ch) {
      FragU pf;
      const int pw = ((ch << 4) + (quad << 2) + (((l15 >> 3) & 1) << 3)) & 31;
      pf.u4 = *(const uint4*)(psw + l15 * 36 + pw);
#pragma unroll
      for (int nt = 0; nt < 4; ++nt) {
        const int d = (nt << 4) + l15;
        const int vw = ((ch << 4) + (quad << 2) + (((d >> 3) & 3) << 2)) & 31;
        FragU vf;
        vf.u4 = *(const uint4*)(vt + d * 36 + vw);
        oacc[nt] = __builtin_amdgcn_mfma_f32_16x16x32_bf16(pf.f, vf.f, oacc[nt], 0, 0, 0);
      }
    }
  }

  // den: reduce across the 16 lanes sharing each row (lane bits 0..3).
#pragma unroll
  for (int r = 0; r < 4; ++r) {
    float d = den[r];
    d += __shfl_xor(d, 1);
    d += __shfl_xor(d, 2);
    d += __shfl_xor(d, 4);
    d += __shfl_xor(d, 8);
    den[r] = kT1 / d;
  }
  const int b = bh >> 3, h = bh & 7;
#pragma unroll
  for (int nt = 0; nt < 4; ++nt) {
#pragma unroll
    for (int r = 0; r < 4; ++r) {
      const int t = t0 + (w << 4) + (quad << 2) + r;
      const int d = (nt << 4) + l15;
      MIX[(t * kBsz + b) * kEmb + (h << 6) + d] = oacc[nt][r] * den[r];
    }
  }
}

// SSA: masked argmax per row (fp32 exact), then MIX += T2 * v[argmax].
__global__ __launch_bounds__(256, 4) void ssa_kernel(
    const float* __restrict__ Q, const float* __restrict__ K,
    const float* __restrict__ V, const float* __restrict__ SEM,
    float* __restrict__ MIX)
{
  __shared__ float ks[64][68];
  __shared__ float rv[64][4];
  __shared__ int   ri[64][4];
  __shared__ int   rowIdx[64];

  const int bh = blockIdx.x;
  const int tBase = blockIdx.y << 6;
  const int tid = threadIdx.x;
  const int r = tid >> 2;
  const int c = tid & 3;

  float4 qreg[16];
  {
    const float* qrow = Q + bh * (kSeq * kHD) + (tBase + r) * kHD;
#pragma unroll
    for (int i = 0; i < 16; ++i) {
      float4 t = *(const float4*)(qrow + (i << 2));
      qreg[i] = make_float4(t.x * kScale, t.y * kScale, t.z * kScale, t.w * kScale);
    }
  }
  float best = -FLT_MAX;
  int bidx = 0;
  const float* semrow = SEM + (tBase + r) * kSeq + (c << 4);

  for (int s0 = 0; s0 < kSeq; s0 += 64) {
    __syncthreads();
    {
      const float* kb = K + bh * (kSeq * kHD) + s0 * kHD;
#pragma unroll
      for (int i = 0; i < 4; ++i) {
        int f = (i << 8) + tid;
        int row = f >> 4, ch = f & 15;
        *(float4*)&ks[row][swz(row, ch)] = *(const float4*)(kb + (row << 6) + (ch << 2));
      }
    }
    __syncthreads();

#pragma unroll 4
    for (int j = 0; j < 16; ++j) {
      const int sl = (c << 4) + j;
      float p0 = 0.f, p1 = 0.f, p2 = 0.f, p3 = 0.f;
#pragma unroll
      for (int i = 0; i < 16; ++i) {
        float4 kk = *(const float4*)&ks[sl][swz(sl, i)];
        p0 = fmaf(qreg[i].x, kk.x, p0);
        p1 = fmaf(qreg[i].y, kk.y, p1);
        p2 = fmaf(qreg[i].z, kk.z, p2);
        p3 = fmaf(qreg[i].w, kk.w, p3);
      }
      const float sc = (p0 + p1) + (p2 + p3);
      const float msk = semrow[s0 + j];
      if (msk >= 0.5f && sc > best) { best = sc; bidx = s0 + sl; }
    }
  }
  rv[r][c] = best;
  ri[r][c] = bidx;
  __syncthreads();
  if (tid < 64) {
    float bb = rv[tid][0];
    int ii = ri[tid][0];
#pragma unroll
    for (int cc = 1; cc < 4; ++cc) {
      float v2 = rv[tid][cc];
      int i2 = ri[tid][cc];
      if (v2 > bb || (v2 == bb && i2 < ii)) { bb = v2; ii = i2; }
    }
    rowIdx[tid] = ii;
  }
  __syncthreads();
  {
    const int s = rowIdx[r];
    const float* vrow = V + bh * (kSeq * kHD) + s * kHD + (c << 4);
    const int t = tBase + r, b = bh >> 3, h = bh & 7;
    float* op = MIX + (t * kBsz + b) * kEmb + (h << 6) + (c << 4);
#pragma unroll
    for (int i = 0; i < 4; ++i) {
      float4 vv = *(const float4*)(vrow + (i << 2));
      float4 o = *(float4*)(op + (i << 2));
      o.x = fmaf(kT2, vv.x, o.x);
      o.y = fmaf(kT2, vv.y, o.y);
      o.z = fmaf(kT2, vv.z, o.z);
      o.w = fmaf(kT2, vv.w, o.w);
      *(float4*)(op + (i << 2)) = o;
    }
  }
}

extern "C" void kernel_launch(void* const* d_in, const int* in_sizes, int n_in,
                              void* d_out, int out_size, void* d_ws, size_t ws_size,
                              hipStream_t stream) {
  const float* query  = (const float*)d_in[0];
  const float* key    = (const float*)d_in[1];
  const float* value  = (const float*)d_in[2];
  const float* qsem   = (const float*)d_in[3];
  const float* ksem   = (const float*)d_in[4];
  const float* semmap = (const float*)d_in[5];
  const float* Wi     = (const float*)d_in[6];
  const float* bi     = (const float*)d_in[7];
  const float* Wo     = (const float*)d_in[8];
  const float* bo     = (const float*)d_in[9];
  float* out = (float*)d_out;

  const size_t kProjElems = (size_t)64 * kSeq * kHD;
  float* P0  = (float*)d_ws;
  float* P1  = P0 + kProjElems;
  float* P2  = P1 + kProjElems;
  float* MIX = P2 + kProjElems;

  const dim3 gg(128, 8);
  const dim3 gs(16, 64);     // t-tile (fast) x bh -> same-bh blocks adjacent
  const dim3 ga(64, 16);

  // SCA projections
  proj_gemm<<<gg, 256, 0, stream>>>(qsem,  Wi, bi, P0, 0,    1);
  proj_gemm<<<gg, 256, 0, stream>>>(ksem,  Wi, bi, P1, 512,  1);
  proj_gemm<<<gg, 256, 0, stream>>>(value, Wi, bi, P2, 1024, 1);
  // SCA attention (MFMA) -> MIX = T1 * o_sca
  sca_mfma<<<gs, 256, 0, stream>>>(P0, P1, P2, semmap, MIX);
  // SSA projections (reuse P0/P1)
  proj_gemm<<<gg, 256, 0, stream>>>(query, Wi, bi, P0, 0,    1);
  proj_gemm<<<gg, 256, 0, stream>>>(key,   Wi, bi, P1, 512,  1);
  // SSA argmax-gather -> MIX += T2 * v[argmax]
  ssa_kernel<<<ga, 256, 0, stream>>>(P0, P1, P2, semmap, MIX);
  // Shared out-projection
  proj_gemm<<<gg, 256, 0, stream>>>(MIX, Wo, bo, out, 0, 0);
}

// Round 3
// 716.703 us; speedup vs baseline: 1.8353x; 1.1470x over previous
//
#include <hip/hip_runtime.h>
#include <float.h>

// ---------------------------------------------------------------------------
// Fused dual-attention (SCA + SSA).  SEQ=1024, B=8, E=512, H=8, HD=64.
//
//  R3 change: ssa_kernel (241us, fp32 VALU/LDS-bound) replaced by ssa_mfma:
//  two-pass screen-then-verify.  Pass 1: bf16 MFMA approx scores -> per-row
//  approx max (margin 0.125 >> 5x the 6.5-sigma bf16 score error ~2e-2).
//  Pass 2: recompute (deterministic), elements within margin get an exact
//  fp32 dot that replicates the R1/R2 summation order bit-for-bit, so the
//  argmax decisions are provably identical to the passing fp32 kernel.
// ---------------------------------------------------------------------------

namespace {
constexpr int kSeq = 1024;
constexpr int kBsz = 8;
constexpr int kEmb = 512;
constexpr int kHD  = 64;
constexpr float kT1 = 0.6f;
constexpr float kT2 = 0.4f;
constexpr float kScale = 0.125f;   // 1/sqrt(64), exact power of two
constexpr float kMargin = 0.125f;  // screen margin >> worst bf16 score error
}

typedef short bf16x8 __attribute__((ext_vector_type(8)));
typedef float f32x4  __attribute__((ext_vector_type(4)));

union FragU { uint4 u4; bf16x8 f; };

__device__ __forceinline__ ushort f2bf(float f) {
  uint u = __float_as_uint(f);
  u += 0x7fff + ((u >> 16) & 1);        // RNE
  return (ushort)(u >> 16);
}
__device__ __forceinline__ uint pack2(float lo, float hi) {
  return (uint)f2bf(lo) | ((uint)f2bf(hi) << 16);
}

// out[m,n] = sum_k X[m,k] * W[woff+n,k] + bias[woff+n]
__global__ __launch_bounds__(256, 4) void proj_gemm(
    const float* __restrict__ X, const float* __restrict__ W,
    const float* __restrict__ bias, float* __restrict__ Out,
    int woff, int headLayout)
{
  __shared__ float As[16][68];
  __shared__ float Bs[16][68];
  const int mBase = blockIdx.x << 6;
  const int nBase = blockIdx.y << 6;
  const int tid = threadIdx.x;
  const int tx = tid & 15, ty = tid >> 4;
  const int sr = tid >> 2;
  const int sk = (tid & 3) << 2;
  const float* xp = X + (mBase + sr) * kEmb + sk;
  const float* wp = W + (woff + nBase + sr) * kEmb + sk;

  float acc[4][4];
#pragma unroll
  for (int i = 0; i < 4; ++i)
#pragma unroll
    for (int j = 0; j < 4; ++j) acc[i][j] = 0.f;

  for (int k0 = 0; k0 < kEmb; k0 += 16) {
    float4 a = *(const float4*)(xp + k0);
    float4 b = *(const float4*)(wp + k0);
    __syncthreads();
    As[sk + 0][sr] = a.x; As[sk + 1][sr] = a.y; As[sk + 2][sr] = a.z; As[sk + 3][sr] = a.w;
    Bs[sk + 0][sr] = b.x; Bs[sk + 1][sr] = b.y; Bs[sk + 2][sr] = b.z; Bs[sk + 3][sr] = b.w;
    __syncthreads();
#pragma unroll
    for (int k = 0; k < 16; ++k) {
      float4 av = *(const float4*)&As[k][ty << 2];
      float4 bv = *(const float4*)&Bs[k][tx << 2];
      float aa[4] = {av.x, av.y, av.z, av.w};
      float bb[4] = {bv.x, bv.y, bv.z, bv.w};
#pragma unroll
      for (int i = 0; i < 4; ++i)
#pragma unroll
        for (int j = 0; j < 4; ++j)
          acc[i][j] = fmaf(aa[i], bb[j], acc[i][j]);
    }
  }
#pragma unroll
  for (int i = 0; i < 4; ++i) {
    const int m = mBase + (ty << 2) + i;
#pragma unroll
    for (int j = 0; j < 4; ++j) {
      const int n = nBase + (tx << 2) + j;
      const float v = acc[i][j] + bias[woff + n];
      if (headLayout) {
        Out[(((m & 7) << 3) + (n >> 6)) * (kSeq * kHD) + ((m >> 3) << 6) + (n & 63)] = v;
      } else {
        Out[m * kEmb + n] = v;
      }
    }
  }
}

// ---------------------------------------------------------------------------
// SCA via MFMA (unchanged from R2).
// ---------------------------------------------------------------------------
__global__ __launch_bounds__(256, 4) void sca_mfma(
    const float* __restrict__ Q, const float* __restrict__ K,
    const float* __restrict__ V, const float* __restrict__ SEM,
    float* __restrict__ MIX)
{
  __shared__ uint ks[64 * 36];
  __shared__ uint vt[64 * 36];
  __shared__ uint ps[4][16 * 36];

  const int t0  = blockIdx.x << 6;
  const int bh  = blockIdx.y;
  const int tid = threadIdx.x;
  const int w    = tid >> 6;
  const int l    = tid & 63;
  const int l15  = l & 15;
  const int quad = l >> 4;

  const float* Qb = Q + bh * (kSeq * kHD);
  const float* Kb = K + bh * (kSeq * kHD);
  const float* Vb = V + bh * (kSeq * kHD);

  FragU qf0, qf1;
  {
    const float* qrow = Qb + (t0 + (w << 4) + l15) * kHD + (quad << 3);
    float4 a = *(const float4*)qrow;
    float4 b = *(const float4*)(qrow + 4);
    float4 c = *(const float4*)(qrow + 32);
    float4 d = *(const float4*)(qrow + 36);
    qf0.u4 = make_uint4(pack2(a.x * kScale, a.y * kScale), pack2(a.z * kScale, a.w * kScale),
                        pack2(b.x * kScale, b.y * kScale), pack2(b.z * kScale, b.w * kScale));
    qf1.u4 = make_uint4(pack2(c.x * kScale, c.y * kScale), pack2(c.z * kScale, c.w * kScale),
                        pack2(d.x * kScale, d.y * kScale), pack2(d.z * kScale, d.w * kScale));
  }

  f32x4 oacc[4];
#pragma unroll
  for (int nt = 0; nt < 4; ++nt) oacc[nt] = (f32x4){0.f, 0.f, 0.f, 0.f};
  float den[4] = {0.f, 0.f, 0.f, 0.f};

  uint* psw = ps[w];

  for (int s0 = 0; s0 < kSeq; s0 += 64) {
    __syncthreads();
    {
      const int sl = tid >> 2, c = tid & 3;
      const float* kp = Kb + (s0 + sl) * kHD + (c << 4);
      float4 k0 = ((const float4*)kp)[0];
      float4 k1 = ((const float4*)kp)[1];
      float4 k2 = ((const float4*)kp)[2];
      float4 k3 = ((const float4*)kp)[3];
      uint* dst = ks + sl * 36 + (c << 3);
      ((uint2*)dst)[0] = make_uint2(pack2(k0.x, k0.y), pack2(k0.z, k0.w));
      ((uint2*)dst)[1] = make_uint2(pack2(k1.x, k1.y), pack2(k1.z, k1.w));
      ((uint2*)dst)[2] = make_uint2(pack2(k2.x, k2.y), pack2(k2.z, k2.w));
      ((uint2*)dst)[3] = make_uint2(pack2(k3.x, k3.y), pack2(k3.z, k3.w));
    }
    {
      const int p = tid >> 3, c7 = tid & 7;
      const float* va = Vb + (s0 + (p << 1)) * kHD + (c7 << 3);
      float4 a0 = ((const float4*)va)[0];
      float4 a1 = ((const float4*)va)[1];
      float4 b0 = ((const float4*)(va + kHD))[0];
      float4 b1 = ((const float4*)(va + kHD))[1];
      const int Wp = (p + ((c7 & 3) << 2)) & 31;
      float av[8] = {a0.x, a0.y, a0.z, a0.w, a1.x, a1.y, a1.z, a1.w};
      float bv[8] = {b0.x, b0.y, b0.z, b0.w, b1.x, b1.y, b1.z, b1.w};
#pragma unroll
      for (int i = 0; i < 8; ++i)
        vt[((c7 << 3) + i) * 36 + Wp] = pack2(av[i], bv[i]);
    }
    __syncthreads();

#pragma unroll
    for (int st = 0; st < 4; ++st) {
      f32x4 sacc = (f32x4){0.f, 0.f, 0.f, 0.f};
      const int srow = (st << 4) + l15;
      FragU kf0, kf1;
      kf0.u4 = *(const uint4*)(ks + srow * 36 + (quad << 2));
      kf1.u4 = *(const uint4*)(ks + srow * 36 + 16 + (quad << 2));
      sacc = __builtin_amdgcn_mfma_f32_16x16x32_bf16(qf0.f, kf0.f, sacc, 0, 0, 0);
      sacc = __builtin_amdgcn_mfma_f32_16x16x32_bf16(qf1.f, kf1.f, sacc, 0, 0, 0);

      const int sg = s0 + (st << 4) + l15;
#pragma unroll
      for (int r = 0; r < 4; ++r) {
        const int trow = (quad << 2) + r;
        const float sem = SEM[(t0 + (w << 4) + trow) * kSeq + sg];
        const float val = (sem < 0.5f) ? 0.f : __expf(sacc[r]);
        den[r] += val;
        const int W  = (st << 3) + (l15 >> 1);
        const int Wp = (W + (((trow >> 3) & 1) << 3)) & 31;
        ushort* p16 = (ushort*)(psw + trow * 36 + Wp);
        p16[l15 & 1] = f2bf(val);
      }
    }
#pragma unroll
    for (int ch = 0; ch < 2; ++ch) {
      FragU pf;
      const int pw = ((ch << 4) + (quad << 2) + (((l15 >> 3) & 1) << 3)) & 31;
      pf.u4 = *(const uint4*)(psw + l15 * 36 + pw);
#pragma unroll
      for (int nt = 0; nt < 4; ++nt) {
        const int d = (nt << 4) + l15;
        const int vw = ((ch << 4) + (quad << 2) + (((d >> 3) & 3) << 2)) & 31;
        FragU vf;
        vf.u4 = *(const uint4*)(vt + d * 36 + vw);
        oacc[nt] = __builtin_amdgcn_mfma_f32_16x16x32_bf16(pf.f, vf.f, oacc[nt], 0, 0, 0);
      }
    }
  }

#pragma unroll
  for (int r = 0; r < 4; ++r) {
    float d = den[r];
    d += __shfl_xor(d, 1);
    d += __shfl_xor(d, 2);
    d += __shfl_xor(d, 4);
    d += __shfl_xor(d, 8);
    den[r] = kT1 / d;
  }
  const int b = bh >> 3, h = bh & 7;
#pragma unroll
  for (int nt = 0; nt < 4; ++nt) {
#pragma unroll
    for (int r = 0; r < 4; ++r) {
      const int t = t0 + (w << 4) + (quad << 2) + r;
      const int d = (nt << 4) + l15;
      MIX[(t * kBsz + b) * kEmb + (h << 6) + d] = oacc[nt][r] * den[r];
    }
  }
}

// ---------------------------------------------------------------------------
// SSA via MFMA screen + exact fp32 verify.
//  Pass 1: bf16 MFMA scores; per-row approx max m~; 64-bit sem mask per
//          (lane,row) so pass 2 never reloads SEM.
//  Pass 2: identical MFMA recompute (deterministic); candidates
//          (s~ >= m~ - margin) get an exact fp32 dot in the SAME summation
//          order as the R1/R2 fp32 kernel (bit-identical decisions).
//  Then cross-lane (val,idx) reduce, gather v[argmax] into MIX.
// ---------------------------------------------------------------------------
__global__ __launch_bounds__(256, 4) void ssa_mfma(
    const float* __restrict__ Q, const float* __restrict__ K,
    const float* __restrict__ V, const float* __restrict__ SEM,
    float* __restrict__ MIX)
{
  __shared__ uint ks[64 * 36];

  const int t0  = blockIdx.x << 6;
  const int bh  = blockIdx.y;
  const int tid = threadIdx.x;
  const int w    = tid >> 6;
  const int l    = tid & 63;
  const int l15  = l & 15;
  const int quad = l >> 4;

  const float* Qb = Q + bh * (kSeq * kHD);
  const float* Kb = K + bh * (kSeq * kHD);

  FragU qf0, qf1;
  {
    const float* qrow = Qb + (t0 + (w << 4) + l15) * kHD + (quad << 3);
    float4 a = *(const float4*)qrow;
    float4 b = *(const float4*)(qrow + 4);
    float4 c = *(const float4*)(qrow + 32);
    float4 d = *(const float4*)(qrow + 36);
    qf0.u4 = make_uint4(pack2(a.x * kScale, a.y * kScale), pack2(a.z * kScale, a.w * kScale),
                        pack2(b.x * kScale, b.y * kScale), pack2(b.z * kScale, b.w * kScale));
    qf1.u4 = make_uint4(pack2(c.x * kScale, c.y * kScale), pack2(c.z * kScale, c.w * kScale),
                        pack2(d.x * kScale, d.y * kScale), pack2(d.z * kScale, d.w * kScale));
  }

  float m4[4] = {-FLT_MAX, -FLT_MAX, -FLT_MAX, -FLT_MAX};
  unsigned long long cmask[4] = {0ull, 0ull, 0ull, 0ull};

  // ---- Pass 1: approx max + sem mask ----
  for (int s0 = 0, tile = 0; s0 < kSeq; s0 += 64, ++tile) {
    __syncthreads();
    {
      const int sl = tid >> 2, c = tid & 3;
      const float* kp = Kb + (s0 + sl) * kHD + (c << 4);
      float4 k0 = ((const float4*)kp)[0];
      float4 k1 = ((const float4*)kp)[1];
      float4 k2 = ((const float4*)kp)[2];
      float4 k3 = ((const float4*)kp)[3];
      uint* dst = ks + sl * 36 + (c << 3);
      ((uint2*)dst)[0] = make_uint2(pack2(k0.x, k0.y), pack2(k0.z, k0.w));
      ((uint2*)dst)[1] = make_uint2(pack2(k1.x, k1.y), pack2(k1.z, k1.w));
      ((uint2*)dst)[2] = make_uint2(pack2(k2.x, k2.y), pack2(k2.z, k2.w));
      ((uint2*)dst)[3] = make_uint2(pack2(k3.x, k3.y), pack2(k3.z, k3.w));
    }
    __syncthreads();

#pragma unroll
    for (int st = 0; st < 4; ++st) {
      f32x4 sacc = (f32x4){0.f, 0.f, 0.f, 0.f};
      const int srow = (st << 4) + l15;
      FragU kf0, kf1;
      kf0.u4 = *(const uint4*)(ks + srow * 36 + (quad << 2));
      kf1.u4 = *(const uint4*)(ks + srow * 36 + 16 + (quad << 2));
      sacc = __builtin_amdgcn_mfma_f32_16x16x32_bf16(qf0.f, kf0.f, sacc, 0, 0, 0);
      sacc = __builtin_amdgcn_mfma_f32_16x16x32_bf16(qf1.f, kf1.f, sacc, 0, 0, 0);

      const int sg = s0 + (st << 4) + l15;
#pragma unroll
      for (int r = 0; r < 4; ++r) {
        const int t = t0 + (w << 4) + (quad << 2) + r;
        const float sem = SEM[t * kSeq + sg];
        if (sem >= 0.5f) {
          m4[r] = fmaxf(m4[r], sacc[r]);
          cmask[r] |= 1ull << ((tile << 2) + st);
        }
      }
    }
  }

#pragma unroll
  for (int r = 0; r < 4; ++r) {
    float m = m4[r];
    m = fmaxf(m, __shfl_xor(m, 1));
    m = fmaxf(m, __shfl_xor(m, 2));
    m = fmaxf(m, __shfl_xor(m, 4));
    m = fmaxf(m, __shfl_xor(m, 8));
    m4[r] = m - kMargin;
  }

  // ---- Pass 2: verify candidates exactly ----
  float best[4] = {-FLT_MAX, -FLT_MAX, -FLT_MAX, -FLT_MAX};
  int   bidx[4] = {kSeq, kSeq, kSeq, kSeq};

  for (int s0 = 0, tile = 0; s0 < kSeq; s0 += 64, ++tile) {
    __syncthreads();
    {
      const int sl = tid >> 2, c = tid & 3;
      const float* kp = Kb + (s0 + sl) * kHD + (c << 4);
      float4 k0 = ((const float4*)kp)[0];
      float4 k1 = ((const float4*)kp)[1];
      float4 k2 = ((const float4*)kp)[2];
      float4 k3 = ((const float4*)kp)[3];
      uint* dst = ks + sl * 36 + (c << 3);
      ((uint2*)dst)[0] = make_uint2(pack2(k0.x, k0.y), pack2(k0.z, k0.w));
      ((uint2*)dst)[1] = make_uint2(pack2(k1.x, k1.y), pack2(k1.z, k1.w));
      ((uint2*)dst)[2] = make_uint2(pack2(k2.x, k2.y), pack2(k2.z, k2.w));
      ((uint2*)dst)[3] = make_uint2(pack2(k3.x, k3.y), pack2(k3.z, k3.w));
    }
    __syncthreads();

#pragma unroll
    for (int st = 0; st < 4; ++st) {
      f32x4 sacc = (f32x4){0.f, 0.f, 0.f, 0.f};
      const int srow = (st << 4) + l15;
      FragU kf0, kf1;
      kf0.u4 = *(const uint4*)(ks + srow * 36 + (quad << 2));
      kf1.u4 = *(const uint4*)(ks + srow * 36 + 16 + (quad << 2));
      sacc = __builtin_amdgcn_mfma_f32_16x16x32_bf16(qf0.f, kf0.f, sacc, 0, 0, 0);
      sacc = __builtin_amdgcn_mfma_f32_16x16x32_bf16(qf1.f, kf1.f, sacc, 0, 0, 0);

      const int sg = s0 + (st << 4) + l15;
#pragma unroll
      for (int r = 0; r < 4; ++r) {
        const bool cand =
            ((cmask[r] >> ((tile << 2) + st)) & 1ull) && (sacc[r] >= m4[r]);
        if (cand) {
          const int t = t0 + (w << 4) + (quad << 2) + r;
          const float* qe = Qb + t * kHD;
          const float* ke = Kb + sg * kHD;
          float p0 = 0.f, p1 = 0.f, p2 = 0.f, p3 = 0.f;
#pragma unroll
          for (int i = 0; i < 16; ++i) {
            float4 qq = *(const float4*)(qe + (i << 2));
            float4 kk = *(const float4*)(ke + (i << 2));
            p0 = fmaf(qq.x, kk.x, p0);
            p1 = fmaf(qq.y, kk.y, p1);
            p2 = fmaf(qq.z, kk.z, p2);
            p3 = fmaf(qq.w, kk.w, p3);
          }
          // x0.125 is an exact pow2 scaling: bit-identical to the R1/R2
          // kernel which pre-scaled q and used the same 4-chain order.
          const float acc = ((p0 + p1) + (p2 + p3)) * kScale;
          if (acc > best[r] || (acc == best[r] && sg < bidx[r])) {
            best[r] = acc;
            bidx[r] = sg;
          }
        }
      }
    }
  }

  // ---- cross-lane (val,idx) reduce + gather ----
  const int b = bh >> 3, h = bh & 7;
#pragma unroll
  for (int r = 0; r < 4; ++r) {
    float v = best[r];
    int   ix = bidx[r];
#pragma unroll
    for (int off = 1; off <= 8; off <<= 1) {
      float v2 = __shfl_xor(v, off);
      int   i2 = __shfl_xor(ix, off);
      if (v2 > v || (v2 == v && i2 < ix)) { v = v2; ix = i2; }
    }
    const int s = (ix < kSeq) ? ix : 0;   // safety clamp (cannot trigger)
    const float* vrow = V + (bh * kSeq + s) * kHD + (l15 << 2);
    float4 vv = *(const float4*)vrow;
    const int t = t0 + (w << 4) + (quad << 2) + r;
    float* op = MIX + (t * kBsz + b) * kEmb + (h << 6) + (l15 << 2);
    float4 o = *(float4*)op;
    o.x = fmaf(kT2, vv.x, o.x);
    o.y = fmaf(kT2, vv.y, o.y);
    o.z = fmaf(kT2, vv.z, o.z);
    o.w = fmaf(kT2, vv.w, o.w);
    *(float4*)op = o;
  }
}

extern "C" void kernel_launch(void* const* d_in, const int* in_sizes, int n_in,
                              void* d_out, int out_size, void* d_ws, size_t ws_size,
                              hipStream_t stream) {
  const float* query  = (const float*)d_in[0];
  const float* key    = (const float*)d_in[1];
  const float* value  = (const float*)d_in[2];
  const float* qsem   = (const float*)d_in[3];
  const float* ksem   = (const float*)d_in[4];
  const float* semmap = (const float*)d_in[5];
  const float* Wi     = (const float*)d_in[6];
  const float* bi     = (const float*)d_in[7];
  const float* Wo     = (const float*)d_in[8];
  const float* bo     = (const float*)d_in[9];
  float* out = (float*)d_out;

  const size_t kProjElems = (size_t)64 * kSeq * kHD;
  float* P0  = (float*)d_ws;
  float* P1  = P0 + kProjElems;
  float* P2  = P1 + kProjElems;
  float* MIX = P2 + kProjElems;

  const dim3 gg(128, 8);
  const dim3 gs(16, 64);     // t-tile x bh

  // SCA projections
  proj_gemm<<<gg, 256, 0, stream>>>(qsem,  Wi, bi, P0, 0,    1);
  proj_gemm<<<gg, 256, 0, stream>>>(ksem,  Wi, bi, P1, 512,  1);
  proj_gemm<<<gg, 256, 0, stream>>>(value, Wi, bi, P2, 1024, 1);
  // SCA attention (MFMA) -> MIX = T1 * o_sca
  sca_mfma<<<gs, 256, 0, stream>>>(P0, P1, P2, semmap, MIX);
  // SSA projections (fp32-exact; feed the argmax) (reuse P0/P1)
  proj_gemm<<<gg, 256, 0, stream>>>(query, Wi, bi, P0, 0,    1);
  proj_gemm<<<gg, 256, 0, stream>>>(key,   Wi, bi, P1, 512,  1);
  // SSA screen+verify -> MIX += T2 * v[argmax]
  ssa_mfma<<<gs, 256, 0, stream>>>(P0, P1, P2, semmap, MIX);
  // Shared out-projection
  proj_gemm<<<gg, 256, 0, stream>>>(MIX, Wo, bo, out, 0, 0);
}

// Round 4
// 470.598 us; speedup vs baseline: 2.7951x; 1.5230x over previous
//
#include <hip/hip_runtime.h>
#include <float.h>

// ---------------------------------------------------------------------------
// Fused dual-attention (SCA + SSA).  SEQ=1024, B=8, E=512, H=8, HD=64.
//
//  R4 changes:
//   * smask_prep: sem_map -> 1-bit masks (16 uint64 per row).
//   * gemm_bf16: MFMA GEMM for qsem/ksem (split-A bf16), value, out-proj.
//   * proj_gemm (query/key): fp32 math byte-identical to R1 (argmax safety);
//     epilogue additionally writes bf16 shadow (Q16 scaled 0.125, K16).
//   * sca_mfma2: reads bf16 Q16/K16 + SMASK; writes bf16 MIX16.
//   * ssa_v3: single-pass screen with per-wave candidate list; exact fp32
//     verify in R1's summation order (decisions bit-identical to R3).
// ---------------------------------------------------------------------------

namespace {
constexpr int kSeq = 1024;
constexpr int kBsz = 8;
constexpr int kEmb = 512;
constexpr int kHD  = 64;
constexpr float kT1 = 0.6f;
constexpr float kT2 = 0.4f;
constexpr float kScale = 0.125f;   // 1/sqrt(64), exact pow2
constexpr float kMargin = 0.125f;  // >> 6.5-sigma bf16 score error (~0.018)
constexpr int kCap = 256;          // per-wave candidate list capacity
}

typedef short bf16x8 __attribute__((ext_vector_type(8)));
typedef float f32x4  __attribute__((ext_vector_type(4)));

union FragU { uint4 u4; bf16x8 f; uint u[4]; };

__device__ __forceinline__ ushort f2bf(float f) {
  uint u = __float_as_uint(f);
  u += 0x7fff + ((u >> 16) & 1);        // RNE
  return (ushort)(u >> 16);
}
__device__ __forceinline__ uint pack2(float lo, float hi) {
  return (uint)f2bf(lo) | ((uint)f2bf(hi) << 16);
}
__device__ __forceinline__ float bf2f(uint h) {     // h = low 16 bits
  return __uint_as_float(h << 16);
}
__device__ __forceinline__ uint monokey(float v) {
  uint u = __float_as_uint(v);
  return (u & 0x80000000u) ? ~u : (u | 0x80000000u);
}

// ---------------------------------------------------------------------------
// sem_map -> bitmask.  SMASK[t*16 + w] bit j = (SEM[t][w*64+j] >= 0.5)
// ---------------------------------------------------------------------------
__global__ void smask_prep(const float* __restrict__ SEM,
                           unsigned long long* __restrict__ SMASK) {
  const int t = blockIdx.x;
  const int w4 = threadIdx.x >> 6;
  const int lane = threadIdx.x & 63;
#pragma unroll
  for (int i = 0; i < 4; ++i) {
    const int word = (w4 << 2) + i;
    const float v = SEM[t * kSeq + (word << 6) + lane];
    unsigned long long m = __ballot(v >= 0.5f);
    if (lane == 0) SMASK[t * 16 + word] = m;
  }
}

// ---------------------------------------------------------------------------
// fp32 proj GEMM — math byte-identical to R1 (feeds SSA exact argmax).
// Adds optional bf16 shadow write (same value, scaled, RNE-rounded).
// ---------------------------------------------------------------------------
__global__ __launch_bounds__(256, 4) void proj_gemm(
    const float* __restrict__ X, const float* __restrict__ W,
    const float* __restrict__ bias, float* __restrict__ Out,
    int woff, ushort* __restrict__ shadow, float sscale)
{
  __shared__ float As[16][68];
  __shared__ float Bs[16][68];
  const int mBase = blockIdx.x << 6;
  const int nBase = blockIdx.y << 6;
  const int tid = threadIdx.x;
  const int tx = tid & 15, ty = tid >> 4;
  const int sr = tid >> 2;
  const int sk = (tid & 3) << 2;
  const float* xp = X + (mBase + sr) * kEmb + sk;
  const float* wp = W + (woff + nBase + sr) * kEmb + sk;

  float acc[4][4];
#pragma unroll
  for (int i = 0; i < 4; ++i)
#pragma unroll
    for (int j = 0; j < 4; ++j) acc[i][j] = 0.f;

  for (int k0 = 0; k0 < kEmb; k0 += 16) {
    float4 a = *(const float4*)(xp + k0);
    float4 b = *(const float4*)(wp + k0);
    __syncthreads();
    As[sk + 0][sr] = a.x; As[sk + 1][sr] = a.y; As[sk + 2][sr] = a.z; As[sk + 3][sr] = a.w;
    Bs[sk + 0][sr] = b.x; Bs[sk + 1][sr] = b.y; Bs[sk + 2][sr] = b.z; Bs[sk + 3][sr] = b.w;
    __syncthreads();
#pragma unroll
    for (int k = 0; k < 16; ++k) {
      float4 av = *(const float4*)&As[k][ty << 2];
      float4 bv = *(const float4*)&Bs[k][tx << 2];
      float aa[4] = {av.x, av.y, av.z, av.w};
      float bb[4] = {bv.x, bv.y, bv.z, bv.w};
#pragma unroll
      for (int i = 0; i < 4; ++i)
#pragma unroll
        for (int j = 0; j < 4; ++j)
          acc[i][j] = fmaf(aa[i], bb[j], acc[i][j]);
    }
  }
#pragma unroll
  for (int i = 0; i < 4; ++i) {
    const int m = mBase + (ty << 2) + i;
#pragma unroll
    for (int j = 0; j < 4; ++j) {
      const int n = nBase + (tx << 2) + j;
      const float v = acc[i][j] + bias[woff + n];
      const int oi = (((m & 7) << 3) + (n >> 6)) * (kSeq * kHD) +
                     ((m >> 3) << 6) + (n & 63);
      Out[oi] = v;
      if (shadow) shadow[oi] = f2bf(v * sscale);
    }
  }
}

// ---------------------------------------------------------------------------
// bf16 MFMA GEMM: out[m,n] = X[m,:] . W[woff+n,:] + bias.
//  aMode: 0 = fp32 X, single bf16; 1 = fp32 X, split hi/lo (2 MFMAs);
//         2 = X already bf16 (row-major [M][512] bf16).
//  outMode: 0 = fp32 plain [M][512]; 1 = bf16 headLayout (scaled).
// Tile 128x64, BK=32, 4 waves (2x2), stride-20-uint LDS (conflict-free b128).
// ---------------------------------------------------------------------------
__global__ __launch_bounds__(256, 2) void gemm_bf16(
    const float* __restrict__ X, const ushort* __restrict__ X16,
    const float* __restrict__ W, const float* __restrict__ bias,
    float* __restrict__ OutF, ushort* __restrict__ Out16,
    int woff, int aMode, int outMode, float scale)
{
  __shared__ uint As[2][128 * 20];
  __shared__ uint Bs[64 * 20];

  const int mBase = blockIdx.x << 7;
  const int nBase = blockIdx.y << 6;
  const int tid = threadIdx.x;
  const int w = tid >> 6;
  const int l = tid & 63;
  const int l15 = l & 15;
  const int quad = l >> 4;
  const int wm = w & 1, wn = w >> 1;

  const int srow = tid >> 1;         // A staging row 0..127
  const int shalf = tid & 1;

  f32x4 acc[4][2];
#pragma unroll
  for (int mi = 0; mi < 4; ++mi)
#pragma unroll
    for (int ni = 0; ni < 2; ++ni) acc[mi][ni] = (f32x4){0.f, 0.f, 0.f, 0.f};

  for (int k0 = 0; k0 < kEmb; k0 += 32) {
    // ---- load global ----
    uint4 ah0, ah1, al0, al1;
    if (aMode == 2) {
      const uint* src = (const uint*)X16 + (size_t)(mBase + srow) * 256 +
                        (k0 >> 1) + (shalf << 3);
      ah0 = ((const uint4*)src)[0];
      ah1 = ((const uint4*)src)[1];
    } else {
      const float* xp = X + (size_t)(mBase + srow) * kEmb + k0 + (shalf << 4);
      float4 f0 = ((const float4*)xp)[0];
      float4 f1 = ((const float4*)xp)[1];
      float4 f2 = ((const float4*)xp)[2];
      float4 f3 = ((const float4*)xp)[3];
      ah0 = make_uint4(pack2(f0.x, f0.y), pack2(f0.z, f0.w),
                       pack2(f1.x, f1.y), pack2(f1.z, f1.w));
      ah1 = make_uint4(pack2(f2.x, f2.y), pack2(f2.z, f2.w),
                       pack2(f3.x, f3.y), pack2(f3.z, f3.w));
      if (aMode == 1) {
        float r[16] = {f0.x, f0.y, f0.z, f0.w, f1.x, f1.y, f1.z, f1.w,
                       f2.x, f2.y, f2.z, f2.w, f3.x, f3.y, f3.z, f3.w};
        uint hi[8] = {ah0.x, ah0.y, ah0.z, ah0.w, ah1.x, ah1.y, ah1.z, ah1.w};
        uint lo[8];
#pragma unroll
        for (int j = 0; j < 8; ++j) {
          float e0 = r[2 * j]     - bf2f(hi[j] & 0xFFFF);
          float e1 = r[2 * j + 1] - bf2f(hi[j] >> 16);
          lo[j] = pack2(e0, e1);
        }
        al0 = make_uint4(lo[0], lo[1], lo[2], lo[3]);
        al1 = make_uint4(lo[4], lo[5], lo[6], lo[7]);
      }
    }
    uint4 bw0, bw1;
    if (tid < 128) {
      const float* wp = W + (size_t)(woff + nBase + srow) * kEmb + k0 + (shalf << 4);
      float4 f0 = ((const float4*)wp)[0];
      float4 f1 = ((const float4*)wp)[1];
      float4 f2 = ((const float4*)wp)[2];
      float4 f3 = ((const float4*)wp)[3];
      bw0 = make_uint4(pack2(f0.x, f0.y), pack2(f0.z, f0.w),
                       pack2(f1.x, f1.y), pack2(f1.z, f1.w));
      bw1 = make_uint4(pack2(f2.x, f2.y), pack2(f2.z, f2.w),
                       pack2(f3.x, f3.y), pack2(f3.z, f3.w));
    }
    __syncthreads();
    {
      uint* dst = As[0] + srow * 20 + (shalf << 3);
      ((uint4*)dst)[0] = ah0;
      ((uint4*)dst)[1] = ah1;
      if (aMode == 1) {
        uint* dstl = As[1] + srow * 20 + (shalf << 3);
        ((uint4*)dstl)[0] = al0;
        ((uint4*)dstl)[1] = al1;
      }
      if (tid < 128) {
        uint* db = Bs + srow * 20 + (shalf << 3);
        ((uint4*)db)[0] = bw0;
        ((uint4*)db)[1] = bw1;
      }
    }
    __syncthreads();

    FragU aF[4], bF[2];
#pragma unroll
    for (int ni = 0; ni < 2; ++ni)
      bF[ni].u4 = *(const uint4*)(Bs + ((wn << 5) + (ni << 4) + l15) * 20 + (quad << 2));
#pragma unroll
    for (int mi = 0; mi < 4; ++mi)
      aF[mi].u4 = *(const uint4*)(As[0] + ((wm << 6) + (mi << 4) + l15) * 20 + (quad << 2));
#pragma unroll
    for (int mi = 0; mi < 4; ++mi)
#pragma unroll
      for (int ni = 0; ni < 2; ++ni)
        acc[mi][ni] = __builtin_amdgcn_mfma_f32_16x16x32_bf16(
            aF[mi].f, bF[ni].f, acc[mi][ni], 0, 0, 0);
    if (aMode == 1) {
#pragma unroll
      for (int mi = 0; mi < 4; ++mi)
        aF[mi].u4 = *(const uint4*)(As[1] + ((wm << 6) + (mi << 4) + l15) * 20 + (quad << 2));
#pragma unroll
      for (int mi = 0; mi < 4; ++mi)
#pragma unroll
        for (int ni = 0; ni < 2; ++ni)
          acc[mi][ni] = __builtin_amdgcn_mfma_f32_16x16x32_bf16(
              aF[mi].f, bF[ni].f, acc[mi][ni], 0, 0, 0);
    }
  }

  // ---- epilogue ----
#pragma unroll
  for (int ni = 0; ni < 2; ++ni) {
    const int n = nBase + (wn << 5) + (ni << 4) + l15;
    const float bv = bias[woff + n];
#pragma unroll
    for (int mi = 0; mi < 4; ++mi) {
#pragma unroll
      for (int r = 0; r < 4; ++r) {
        const int m = mBase + (wm << 6) + (mi << 4) + (quad << 2) + r;
        const float v = acc[mi][ni][r] + bv;
        if (outMode == 0) {
          OutF[(size_t)m * kEmb + n] = v;
        } else {
          const int oi = (((m & 7) << 3) + (n >> 6)) * (kSeq * kHD) +
                         ((m >> 3) << 6) + (n & 63);
          Out16[oi] = f2bf(v * scale);
        }
      }
    }
  }
}

// ---------------------------------------------------------------------------
// SCA: bf16 Q16 (pre-scaled) / K16, fp32... V16 bf16, SMASK bits, MIX16 out.
// ---------------------------------------------------------------------------
__global__ __launch_bounds__(256, 4) void sca_mfma2(
    const ushort* __restrict__ Q16, const ushort* __restrict__ K16,
    const ushort* __restrict__ V16,
    const unsigned long long* __restrict__ SMASK,
    ushort* __restrict__ MIX16)
{
  __shared__ uint ks[64 * 36];
  __shared__ uint vt[64 * 36];
  __shared__ uint ps[4][16 * 36];

  const int t0  = blockIdx.x << 6;
  const int bh  = blockIdx.y;
  const int tid = threadIdx.x;
  const int w    = tid >> 6;
  const int l    = tid & 63;
  const int l15  = l & 15;
  const int quad = l >> 4;

  const uint* Qu = (const uint*)Q16 + (size_t)bh * (kSeq * 32);
  const uint* Ku = (const uint*)K16 + (size_t)bh * (kSeq * 32);
  const uint* Vu = (const uint*)V16 + (size_t)bh * (kSeq * 32);

  FragU qf0, qf1;
  {
    const uint* qrow = Qu + (size_t)(t0 + (w << 4) + l15) * 32;
    qf0.u4 = *(const uint4*)(qrow + (quad << 2));
    qf1.u4 = *(const uint4*)(qrow + 16 + (quad << 2));
  }

  f32x4 oacc[4];
#pragma unroll
  for (int nt = 0; nt < 4; ++nt) oacc[nt] = (f32x4){0.f, 0.f, 0.f, 0.f};
  float den[4] = {0.f, 0.f, 0.f, 0.f};

  uint* psw = ps[w];

  for (int s0 = 0, tile = 0; s0 < kSeq; s0 += 64, ++tile) {
    __syncthreads();
    {   // K tile: 64 rows x 32 uints
      const int sl = tid >> 2, c = tid & 3;
      const uint* kp = Ku + (size_t)(s0 + sl) * 32 + (c << 3);
      uint4 a = ((const uint4*)kp)[0];
      uint4 b = ((const uint4*)kp)[1];
      uint* dst = ks + sl * 36 + (c << 3);
      ((uint4*)dst)[0] = a;
      ((uint4*)dst)[1] = b;
    }
    {   // V^T tile from bf16 V16
      const int p = tid >> 3, c7 = tid & 7;
      const uint* va = Vu + (size_t)(s0 + (p << 1)) * 32 + (c7 << 2);
      FragU A, B;
      A.u4 = *(const uint4*)va;
      B.u4 = *(const uint4*)(va + 32);
      const int Wp = (p + ((c7 & 3) << 2)) & 31;
#pragma unroll
      for (int i = 0; i < 8; ++i) {
        uint ai = (A.u[i >> 1] >> ((i & 1) << 4)) & 0xFFFF;
        uint bi = (B.u[i >> 1] >> ((i & 1) << 4)) & 0xFFFF;
        vt[((c7 << 3) + i) * 36 + Wp] = ai | (bi << 16);
      }
    }
    __syncthreads();

    unsigned long long wv[4];
#pragma unroll
    for (int r = 0; r < 4; ++r)
      wv[r] = SMASK[(size_t)(t0 + (w << 4) + (quad << 2) + r) * 16 + tile];

#pragma unroll
    for (int st = 0; st < 4; ++st) {
      f32x4 sacc = (f32x4){0.f, 0.f, 0.f, 0.f};
      const int srow = (st << 4) + l15;
      FragU kf0, kf1;
      kf0.u4 = *(const uint4*)(ks + srow * 36 + (quad << 2));
      kf1.u4 = *(const uint4*)(ks + srow * 36 + 16 + (quad << 2));
      sacc = __builtin_amdgcn_mfma_f32_16x16x32_bf16(qf0.f, kf0.f, sacc, 0, 0, 0);
      sacc = __builtin_amdgcn_mfma_f32_16x16x32_bf16(qf1.f, kf1.f, sacc, 0, 0, 0);

#pragma unroll
      for (int r = 0; r < 4; ++r) {
        const int trow = (quad << 2) + r;
        const uint bit = (uint)(wv[r] >> ((st << 4) + l15)) & 1u;
        const float val = bit ? __expf(sacc[r]) : 0.f;
        den[r] += val;
        const int W  = (st << 3) + (l15 >> 1);
        const int Wp = (W + (((trow >> 3) & 1) << 3)) & 31;
        ushort* p16 = (ushort*)(psw + trow * 36 + Wp);
        p16[l15 & 1] = f2bf(val);
      }
    }
#pragma unroll
    for (int ch = 0; ch < 2; ++ch) {
      FragU pf;
      const int pw = ((ch << 4) + (quad << 2) + (((l15 >> 3) & 1) << 3)) & 31;
      pf.u4 = *(const uint4*)(psw + l15 * 36 + pw);
#pragma unroll
      for (int nt = 0; nt < 4; ++nt) {
        const int d = (nt << 4) + l15;
        const int vw = ((ch << 4) + (quad << 2) + (((d >> 3) & 3) << 2)) & 31;
        FragU vf;
        vf.u4 = *(const uint4*)(vt + d * 36 + vw);
        oacc[nt] = __builtin_amdgcn_mfma_f32_16x16x32_bf16(pf.f, vf.f, oacc[nt], 0, 0, 0);
      }
    }
  }

#pragma unroll
  for (int r = 0; r < 4; ++r) {
    float d = den[r];
    d += __shfl_xor(d, 1);
    d += __shfl_xor(d, 2);
    d += __shfl_xor(d, 4);
    d += __shfl_xor(d, 8);
    den[r] = kT1 / d;
  }
  const int b = bh >> 3, h = bh & 7;
#pragma unroll
  for (int nt = 0; nt < 4; ++nt) {
#pragma unroll
    for (int r = 0; r < 4; ++r) {
      const int t = t0 + (w << 4) + (quad << 2) + r;
      const int d = (nt << 4) + l15;
      MIX16[(size_t)(t * kBsz + b) * kEmb + (h << 6) + d] =
          f2bf(oacc[nt][r] * den[r]);
    }
  }
}

// ---------------------------------------------------------------------------
// SSA single-pass: bf16 MFMA screen with running cross-lane max; candidates
// within margin recorded to per-wave list (superset-correct); survivors get
// the exact fp32 dot in R1's order; per-row resolve via 64-bit atomicMax.
// Block: 512 threads (8 waves, 128 t-rows).  Grid (8, 64).
// ---------------------------------------------------------------------------
__global__ __launch_bounds__(512, 2) void ssa_v3(
    const ushort* __restrict__ Q16, const ushort* __restrict__ K16,
    const float* __restrict__ Qf, const float* __restrict__ Kf,
    const ushort* __restrict__ V16,
    const unsigned long long* __restrict__ SMASK,
    ushort* __restrict__ MIX16)
{
  __shared__ uint ks[64 * 36];
  __shared__ uint2 list[8][kCap];
  __shared__ float thrL[8][16];
  __shared__ unsigned long long key64L[8][16];
  __shared__ uint cnt[8];

  const int t0  = blockIdx.x << 7;
  const int bh  = blockIdx.y;
  const int tid = threadIdx.x;
  const int w    = tid >> 6;
  const int l    = tid & 63;
  const int l15  = l & 15;
  const int quad = l >> 4;

  if (tid < 8) cnt[tid] = 0;
  if (tid < 128) ((unsigned long long*)key64L)[tid] = 0ull;

  const uint* Qu = (const uint*)Q16 + (size_t)bh * (kSeq * 32);
  const uint* Ku = (const uint*)K16 + (size_t)bh * (kSeq * 32);

  FragU qf0, qf1;
  {
    const uint* qrow = Qu + (size_t)(t0 + (w << 4) + l15) * 32;
    qf0.u4 = *(const uint4*)(qrow + (quad << 2));
    qf1.u4 = *(const uint4*)(qrow + 16 + (quad << 2));
  }

  float m4[4] = {-FLT_MAX, -FLT_MAX, -FLT_MAX, -FLT_MAX};

  for (int s0 = 0, tile = 0; s0 < kSeq; s0 += 64, ++tile) {
    __syncthreads();
    {   // stage K16 tile: 512 threads x 16 B
      const int row = tid >> 3, c = tid & 7;
      uint4 a = *(const uint4*)(Ku + (size_t)(s0 + row) * 32 + (c << 2));
      *(uint4*)(ks + row * 36 + (c << 2)) = a;
    }
    __syncthreads();

    unsigned long long wv[4];
#pragma unroll
    for (int r = 0; r < 4; ++r)
      wv[r] = SMASK[(size_t)(t0 + (w << 4) + (quad << 2) + r) * 16 + tile];

    f32x4 sv[4];
#pragma unroll
    for (int st = 0; st < 4; ++st) {
      f32x4 sacc = (f32x4){0.f, 0.f, 0.f, 0.f};
      const int srow = (st << 4) + l15;
      FragU kf0, kf1;
      kf0.u4 = *(const uint4*)(ks + srow * 36 + (quad << 2));
      kf1.u4 = *(const uint4*)(ks + srow * 36 + 16 + (quad << 2));
      sacc = __builtin_amdgcn_mfma_f32_16x16x32_bf16(qf0.f, kf0.f, sacc, 0, 0, 0);
      sacc = __builtin_amdgcn_mfma_f32_16x16x32_bf16(qf1.f, kf1.f, sacc, 0, 0, 0);
      sv[st] = sacc;
#pragma unroll
      for (int r = 0; r < 4; ++r) {
        const uint bit = (uint)(wv[r] >> ((st << 4) + l15)) & 1u;
        if (bit) m4[r] = fmaxf(m4[r], sacc[r]);
      }
    }
    // cross-lane running max (16 lanes per row share lane bits 0..3)
#pragma unroll
    for (int r = 0; r < 4; ++r) {
      float m = m4[r];
      m = fmaxf(m, __shfl_xor(m, 1));
      m = fmaxf(m, __shfl_xor(m, 2));
      m = fmaxf(m, __shfl_xor(m, 4));
      m = fmaxf(m, __shfl_xor(m, 8));
      m4[r] = m;
    }
    // record candidates vs tightened running threshold (superset of final)
#pragma unroll
    for (int st = 0; st < 4; ++st) {
#pragma unroll
      for (int r = 0; r < 4; ++r) {
        const uint bit = (uint)(wv[r] >> ((st << 4) + l15)) & 1u;
        const float x = sv[st][r];
        if (bit && x >= m4[r] - kMargin) {
          uint idx = atomicAdd(&cnt[w], 1u);
          if (idx < (uint)kCap) {
            const int rowid = (quad << 2) + r;
            const int s = s0 + (st << 4) + l15;
            list[w][idx] = make_uint2(__float_as_uint(x),
                                      ((uint)rowid << 10) | (uint)s);
          }
        }
      }
    }
  }

  // final thresholds to LDS
  if (l15 == 0) {
#pragma unroll
    for (int r = 0; r < 4; ++r) thrL[w][(quad << 2) + r] = m4[r] - kMargin;
  }
  __syncthreads();

  // verify survivors with the EXACT R1-order fp32 dot
  const uint n = min(cnt[w], (uint)kCap);
  const float* Qbf = Qf + (size_t)bh * (kSeq * kHD);
  const float* Kbf = Kf + (size_t)bh * (kSeq * kHD);
  for (uint base = 0; base < n; base += 64) {
    const uint e = base + (uint)l;
    if (e < n) {
      const uint2 ent = list[w][e];
      const uint rowid = ent.y >> 10;
      const uint s = ent.y & 1023u;
      const float xv = __uint_as_float(ent.x);
      if (xv >= thrL[w][rowid]) {
        const int t = t0 + (w << 4) + (int)rowid;
        const float* qe = Qbf + (size_t)t * kHD;
        const float* ke = Kbf + (size_t)s * kHD;
        float p0 = 0.f, p1 = 0.f, p2 = 0.f, p3 = 0.f;
#pragma unroll
        for (int i = 0; i < 16; ++i) {
          float4 qq = *(const float4*)(qe + (i << 2));
          float4 kk = *(const float4*)(ke + (i << 2));
          p0 = fmaf(qq.x, kk.x, p0);
          p1 = fmaf(qq.y, kk.y, p1);
          p2 = fmaf(qq.z, kk.z, p2);
          p3 = fmaf(qq.w, kk.w, p3);
        }
        const float acc = ((p0 + p1) + (p2 + p3)) * kScale;
        const unsigned long long key =
            ((unsigned long long)monokey(acc) << 16) |
            (unsigned long long)(1023u - s);
        atomicMax(&key64L[w][rowid], key);
      }
    }
  }
  __syncthreads();

  // gather v16[argmax] into MIX16
  const int b = bh >> 3, h = bh & 7;
  const uint* Vu = (const uint*)V16 + (size_t)bh * (kSeq * 32);
#pragma unroll
  for (int r = 0; r < 4; ++r) {
    const int rowid = (quad << 2) + r;
    const unsigned long long key = key64L[w][rowid];
    const uint s = 1023u - (uint)(key & 0xFFFFull);
    const uint2 vv = *(const uint2*)(Vu + (size_t)s * 32 + (l15 << 1));
    const int t = t0 + (w << 4) + rowid;
    uint* op = (uint*)MIX16 + ((size_t)(t * kBsz + b) * kEmb + (h << 6)) / 2 + (l15 << 1);
    uint2 o = *(uint2*)op;
    float o0 = bf2f(o.x & 0xFFFF) + kT2 * bf2f(vv.x & 0xFFFF);
    float o1 = bf2f(o.x >> 16)    + kT2 * bf2f(vv.x >> 16);
    float o2 = bf2f(o.y & 0xFFFF) + kT2 * bf2f(vv.y & 0xFFFF);
    float o3 = bf2f(o.y >> 16)    + kT2 * bf2f(vv.y >> 16);
    *(uint2*)op = make_uint2(pack2(o0, o1), pack2(o2, o3));
  }
}

extern "C" void kernel_launch(void* const* d_in, const int* in_sizes, int n_in,
                              void* d_out, int out_size, void* d_ws, size_t ws_size,
                              hipStream_t stream) {
  const float* query  = (const float*)d_in[0];
  const float* key    = (const float*)d_in[1];
  const float* value  = (const float*)d_in[2];
  const float* qsem   = (const float*)d_in[3];
  const float* ksem   = (const float*)d_in[4];
  const float* semmap = (const float*)d_in[5];
  const float* Wi     = (const float*)d_in[6];
  const float* bi     = (const float*)d_in[7];
  const float* Wo     = (const float*)d_in[8];
  const float* bo     = (const float*)d_in[9];
  float* out = (float*)d_out;

  char* ws = (char*)d_ws;
  unsigned long long* SMASK = (unsigned long long*)ws;          ws += 1024 * 16 * 8;
  ushort* Q16  = (ushort*)ws;  ws += (size_t)64 * kSeq * kHD * 2;   // 8 MB
  ushort* K16  = (ushort*)ws;  ws += (size_t)64 * kSeq * kHD * 2;   // 8 MB
  ushort* V16  = (ushort*)ws;  ws += (size_t)64 * kSeq * kHD * 2;   // 8 MB
  ushort* MIX16 = (ushort*)ws; ws += (size_t)kSeq * kBsz * kEmb * 2; // 8 MB
  float* P1 = (float*)ws;      ws += (size_t)64 * kSeq * kHD * 4;   // 16 MB
  float* P0 = out;   // d_out is dead until the final GEMM: use as fp32 Q proj

  const dim3 gg(128, 8);     // fp32 proj grid
  const dim3 gb(64, 8);      // bf16 gemm grid (128x64 tiles)
  const dim3 gs(16, 64);     // sca: t-tile x bh
  const dim3 gv(8, 64);      // ssa: 128-row t-tile x bh

  smask_prep<<<1024, 256, 0, stream>>>(semmap, SMASK);
  // SCA projections (bf16 MFMA; split-A for q/k to limit score error)
  gemm_bf16<<<gb, 256, 0, stream>>>(qsem, nullptr, Wi, bi, nullptr, Q16,
                                    0, 1, 1, kScale);
  gemm_bf16<<<gb, 256, 0, stream>>>(ksem, nullptr, Wi, bi, nullptr, K16,
                                    512, 1, 1, 1.0f);
  gemm_bf16<<<gb, 256, 0, stream>>>(value, nullptr, Wi, bi, nullptr, V16,
                                    1024, 0, 1, 1.0f);
  // SCA attention -> MIX16 = bf16(T1 * o_sca)
  sca_mfma2<<<gs, 256, 0, stream>>>(Q16, K16, V16, SMASK, MIX16);
  // SSA projections: fp32 math identical to R1 + bf16 shadows
  proj_gemm<<<gg, 256, 0, stream>>>(query, Wi, bi, P0, 0,   Q16, kScale);
  proj_gemm<<<gg, 256, 0, stream>>>(key,   Wi, bi, P1, 512, K16, 1.0f);
  // SSA screen+verify -> MIX16 += bf16(T2 * v[argmax])
  ssa_v3<<<gv, 512, 0, stream>>>(Q16, K16, P0, P1, V16, SMASK, MIX16);
  // Out projection (reads bf16 MIX16 directly)
  gemm_bf16<<<gb, 256, 0, stream>>>(nullptr, MIX16, Wo, bo, out, nullptr,
                                    0, 2, 0, 1.0f);
}

// Round 5
// 448.237 us; speedup vs baseline: 2.9345x; 1.0499x over previous
//
#include <hip/hip_runtime.h>
#include <float.h>

// ---------------------------------------------------------------------------
// Fused dual-attention (SCA + SSA).  SEQ=1024, B=8, E=512, H=8, HD=64.
//
//  R5 changes:
//   * proj_v2 replaces proj_gemm: 128x64 tile, 8x4 regs/thread, BK=32.
//     Per-output fma chain is STILL one accumulator, k ascending 0..511,
//     then +bias -> bit-identical to R1 (SSA argmax decisions preserved).
//   * gemm_bf16: split-A removed (bf16 output rounding dominates anyway);
//     LDS 25.6 -> 15.4 KB.
// ---------------------------------------------------------------------------

namespace {
constexpr int kSeq = 1024;
constexpr int kBsz = 8;
constexpr int kEmb = 512;
constexpr int kHD  = 64;
constexpr float kT1 = 0.6f;
constexpr float kT2 = 0.4f;
constexpr float kScale = 0.125f;   // 1/sqrt(64), exact pow2
constexpr float kMargin = 0.125f;  // >> 6.5-sigma bf16 score error (~0.018)
constexpr int kCap = 256;          // per-wave candidate list capacity
}

typedef short bf16x8 __attribute__((ext_vector_type(8)));
typedef float f32x4  __attribute__((ext_vector_type(4)));

union FragU { uint4 u4; bf16x8 f; uint u[4]; };

__device__ __forceinline__ ushort f2bf(float f) {
  uint u = __float_as_uint(f);
  u += 0x7fff + ((u >> 16) & 1);        // RNE
  return (ushort)(u >> 16);
}
__device__ __forceinline__ uint pack2(float lo, float hi) {
  return (uint)f2bf(lo) | ((uint)f2bf(hi) << 16);
}
__device__ __forceinline__ float bf2f(uint h) {     // h = low 16 bits
  return __uint_as_float(h << 16);
}
__device__ __forceinline__ uint monokey(float v) {
  uint u = __float_as_uint(v);
  return (u & 0x80000000u) ? ~u : (u | 0x80000000u);
}

// ---------------------------------------------------------------------------
// sem_map -> bitmask.  SMASK[t*16 + w] bit j = (SEM[t][w*64+j] >= 0.5)
// ---------------------------------------------------------------------------
__global__ void smask_prep(const float* __restrict__ SEM,
                           unsigned long long* __restrict__ SMASK) {
  const int t = blockIdx.x;
  const int w4 = threadIdx.x >> 6;
  const int lane = threadIdx.x & 63;
#pragma unroll
  for (int i = 0; i < 4; ++i) {
    const int word = (w4 << 2) + i;
    const float v = SEM[t * kSeq + (word << 6) + lane];
    unsigned long long m = __ballot(v >= 0.5f);
    if (lane == 0) SMASK[t * 16 + word] = m;
  }
}

// ---------------------------------------------------------------------------
// fp32 proj GEMM v2 — per-element math byte-identical to R1:
// single accumulator, fma chain k=0..511 ascending, then +bias.
// Tile 128x64, 256 threads, per-thread 8 rows x 4 cols, BK=32.
// Writes head-layout fp32 + bf16 shadow (scaled, RNE).
// ---------------------------------------------------------------------------
__global__ __launch_bounds__(256, 4) void proj_v2(
    const float* __restrict__ X, const float* __restrict__ W,
    const float* __restrict__ bias, float* __restrict__ Out,
    int woff, ushort* __restrict__ shadow, float sscale)
{
  __shared__ float As[32 * 132];   // [k][m], 128 m + pad 4
  __shared__ float Bs[32 * 68];    // [k][n], 64 n + pad 4

  const int mBase = blockIdx.x << 7;
  const int nBase = blockIdx.y << 6;
  const int tid = threadIdx.x;
  const int tx = tid & 15;        // col group: n = nBase + tx*4 + j
  const int my = tid >> 4;        // row group: m = mBase + my*8 + i
  const int ar = tid >> 1, ah = (tid & 1) << 4;   // A staging: row, k-half
  const int br = tid >> 2, bk = (tid & 3) << 3;   // B staging: row, k-oct

  float acc[8][4];
#pragma unroll
  for (int i = 0; i < 8; ++i)
#pragma unroll
    for (int j = 0; j < 4; ++j) acc[i][j] = 0.f;

  const float* xp = X + (size_t)(mBase + ar) * kEmb + ah;
  const float* wp = W + (size_t)(woff + nBase + br) * kEmb + bk;

  for (int k0 = 0; k0 < kEmb; k0 += 32) {
    float4 a0 = ((const float4*)(xp + k0))[0];
    float4 a1 = ((const float4*)(xp + k0))[1];
    float4 a2 = ((const float4*)(xp + k0))[2];
    float4 a3 = ((const float4*)(xp + k0))[3];
    float4 b0 = ((const float4*)(wp + k0))[0];
    float4 b1 = ((const float4*)(wp + k0))[1];
    __syncthreads();
    {
      float av[16] = {a0.x, a0.y, a0.z, a0.w, a1.x, a1.y, a1.z, a1.w,
                      a2.x, a2.y, a2.z, a2.w, a3.x, a3.y, a3.z, a3.w};
#pragma unroll
      for (int i = 0; i < 16; ++i) As[(ah + i) * 132 + ar] = av[i];
      float bv[8] = {b0.x, b0.y, b0.z, b0.w, b1.x, b1.y, b1.z, b1.w};
#pragma unroll
      for (int i = 0; i < 8; ++i) Bs[(bk + i) * 68 + br] = bv[i];
    }
    __syncthreads();

#pragma unroll 8
    for (int k = 0; k < 32; ++k) {
      float4 A0 = *(const float4*)&As[k * 132 + (my << 3)];
      float4 A1 = *(const float4*)&As[k * 132 + (my << 3) + 4];
      float4 Bv = *(const float4*)&Bs[k * 68 + (tx << 2)];
      float aa[8] = {A0.x, A0.y, A0.z, A0.w, A1.x, A1.y, A1.z, A1.w};
      float bb[4] = {Bv.x, Bv.y, Bv.z, Bv.w};
#pragma unroll
      for (int i = 0; i < 8; ++i)
#pragma unroll
        for (int j = 0; j < 4; ++j)
          acc[i][j] = fmaf(aa[i], bb[j], acc[i][j]);
    }
  }

#pragma unroll
  for (int i = 0; i < 8; ++i) {
    const int m = mBase + (my << 3) + i;
#pragma unroll
    for (int j = 0; j < 4; ++j) {
      const int n = nBase + (tx << 2) + j;
      const float v = acc[i][j] + bias[woff + n];
      const int oi = (((m & 7) << 3) + (n >> 6)) * (kSeq * kHD) +
                     ((m >> 3) << 6) + (n & 63);
      Out[oi] = v;
      shadow[oi] = f2bf(v * sscale);
    }
  }
}

// ---------------------------------------------------------------------------
// bf16 MFMA GEMM: out[m,n] = X[m,:] . W[woff+n,:] + bias.
//  aMode: 0 = fp32 X (converted in staging); 2 = X already bf16 row-major.
//  outMode: 0 = fp32 plain [M][512]; 1 = bf16 headLayout (scaled).
// Tile 128x64, BK=32, 4 waves (2x2), stride-20-uint LDS.
// ---------------------------------------------------------------------------
__global__ __launch_bounds__(256, 2) void gemm_bf16(
    const float* __restrict__ X, const ushort* __restrict__ X16,
    const float* __restrict__ W, const float* __restrict__ bias,
    float* __restrict__ OutF, ushort* __restrict__ Out16,
    int woff, int aMode, int outMode, float scale)
{
  __shared__ uint As[128 * 20];
  __shared__ uint Bs[64 * 20];

  const int mBase = blockIdx.x << 7;
  const int nBase = blockIdx.y << 6;
  const int tid = threadIdx.x;
  const int w = tid >> 6;
  const int l = tid & 63;
  const int l15 = l & 15;
  const int quad = l >> 4;
  const int wm = w & 1, wn = w >> 1;

  const int srow = tid >> 1;         // A staging row 0..127
  const int shalf = tid & 1;

  f32x4 acc[4][2];
#pragma unroll
  for (int mi = 0; mi < 4; ++mi)
#pragma unroll
    for (int ni = 0; ni < 2; ++ni) acc[mi][ni] = (f32x4){0.f, 0.f, 0.f, 0.f};

  for (int k0 = 0; k0 < kEmb; k0 += 32) {
    // ---- load global ----
    uint4 ah0, ah1;
    if (aMode == 2) {
      const uint* src = (const uint*)X16 + (size_t)(mBase + srow) * 256 +
                        (k0 >> 1) + (shalf << 3);
      ah0 = ((const uint4*)src)[0];
      ah1 = ((const uint4*)src)[1];
    } else {
      const float* xp = X + (size_t)(mBase + srow) * kEmb + k0 + (shalf << 4);
      float4 f0 = ((const float4*)xp)[0];
      float4 f1 = ((const float4*)xp)[1];
      float4 f2 = ((const float4*)xp)[2];
      float4 f3 = ((const float4*)xp)[3];
      ah0 = make_uint4(pack2(f0.x, f0.y), pack2(f0.z, f0.w),
                       pack2(f1.x, f1.y), pack2(f1.z, f1.w));
      ah1 = make_uint4(pack2(f2.x, f2.y), pack2(f2.z, f2.w),
                       pack2(f3.x, f3.y), pack2(f3.z, f3.w));
    }
    uint4 bw0, bw1;
    if (tid < 128) {
      const float* wp = W + (size_t)(woff + nBase + srow) * kEmb + k0 + (shalf << 4);
      float4 f0 = ((const float4*)wp)[0];
      float4 f1 = ((const float4*)wp)[1];
      float4 f2 = ((const float4*)wp)[2];
      float4 f3 = ((const float4*)wp)[3];
      bw0 = make_uint4(pack2(f0.x, f0.y), pack2(f0.z, f0.w),
                       pack2(f1.x, f1.y), pack2(f1.z, f1.w));
      bw1 = make_uint4(pack2(f2.x, f2.y), pack2(f2.z, f2.w),
                       pack2(f3.x, f3.y), pack2(f3.z, f3.w));
    }
    __syncthreads();
    {
      uint* dst = As + srow * 20 + (shalf << 3);
      ((uint4*)dst)[0] = ah0;
      ((uint4*)dst)[1] = ah1;
      if (tid < 128) {
        uint* db = Bs + srow * 20 + (shalf << 3);
        ((uint4*)db)[0] = bw0;
        ((uint4*)db)[1] = bw1;
      }
    }
    __syncthreads();

    FragU aF[4], bF[2];
#pragma unroll
    for (int ni = 0; ni < 2; ++ni)
      bF[ni].u4 = *(const uint4*)(Bs + ((wn << 5) + (ni << 4) + l15) * 20 + (quad << 2));
#pragma unroll
    for (int mi = 0; mi < 4; ++mi)
      aF[mi].u4 = *(const uint4*)(As + ((wm << 6) + (mi << 4) + l15) * 20 + (quad << 2));
#pragma unroll
    for (int mi = 0; mi < 4; ++mi)
#pragma unroll
      for (int ni = 0; ni < 2; ++ni)
        acc[mi][ni] = __builtin_amdgcn_mfma_f32_16x16x32_bf16(
            aF[mi].f, bF[ni].f, acc[mi][ni], 0, 0, 0);
  }

  // ---- epilogue ----
#pragma unroll
  for (int ni = 0; ni < 2; ++ni) {
    const int n = nBase + (wn << 5) + (ni << 4) + l15;
    const float bv = bias[woff + n];
#pragma unroll
    for (int mi = 0; mi < 4; ++mi) {
#pragma unroll
      for (int r = 0; r < 4; ++r) {
        const int m = mBase + (wm << 6) + (mi << 4) + (quad << 2) + r;
        const float v = acc[mi][ni][r] + bv;
        if (outMode == 0) {
          OutF[(size_t)m * kEmb + n] = v;
        } else {
          const int oi = (((m & 7) << 3) + (n >> 6)) * (kSeq * kHD) +
                         ((m >> 3) << 6) + (n & 63);
          Out16[oi] = f2bf(v * scale);
        }
      }
    }
  }
}

// ---------------------------------------------------------------------------
// SCA: bf16 Q16 (pre-scaled) / K16 / V16, SMASK bits, MIX16 out.
// ---------------------------------------------------------------------------
__global__ __launch_bounds__(256, 4) void sca_mfma2(
    const ushort* __restrict__ Q16, const ushort* __restrict__ K16,
    const ushort* __restrict__ V16,
    const unsigned long long* __restrict__ SMASK,
    ushort* __restrict__ MIX16)
{
  __shared__ uint ks[64 * 36];
  __shared__ uint vt[64 * 36];
  __shared__ uint ps[4][16 * 36];

  const int t0  = blockIdx.x << 6;
  const int bh  = blockIdx.y;
  const int tid = threadIdx.x;
  const int w    = tid >> 6;
  const int l    = tid & 63;
  const int l15  = l & 15;
  const int quad = l >> 4;

  const uint* Qu = (const uint*)Q16 + (size_t)bh * (kSeq * 32);
  const uint* Ku = (const uint*)K16 + (size_t)bh * (kSeq * 32);
  const uint* Vu = (const uint*)V16 + (size_t)bh * (kSeq * 32);

  FragU qf0, qf1;
  {
    const uint* qrow = Qu + (size_t)(t0 + (w << 4) + l15) * 32;
    qf0.u4 = *(const uint4*)(qrow + (quad << 2));
    qf1.u4 = *(const uint4*)(qrow + 16 + (quad << 2));
  }

  f32x4 oacc[4];
#pragma unroll
  for (int nt = 0; nt < 4; ++nt) oacc[nt] = (f32x4){0.f, 0.f, 0.f, 0.f};
  float den[4] = {0.f, 0.f, 0.f, 0.f};

  uint* psw = ps[w];

  for (int s0 = 0, tile = 0; s0 < kSeq; s0 += 64, ++tile) {
    __syncthreads();
    {   // K tile: 64 rows x 32 uints
      const int sl = tid >> 2, c = tid & 3;
      const uint* kp = Ku + (size_t)(s0 + sl) * 32 + (c << 3);
      uint4 a = ((const uint4*)kp)[0];
      uint4 b = ((const uint4*)kp)[1];
      uint* dst = ks + sl * 36 + (c << 3);
      ((uint4*)dst)[0] = a;
      ((uint4*)dst)[1] = b;
    }
    {   // V^T tile from bf16 V16
      const int p = tid >> 3, c7 = tid & 7;
      const uint* va = Vu + (size_t)(s0 + (p << 1)) * 32 + (c7 << 2);
      FragU A, B;
      A.u4 = *(const uint4*)va;
      B.u4 = *(const uint4*)(va + 32);
      const int Wp = (p + ((c7 & 3) << 2)) & 31;
#pragma unroll
      for (int i = 0; i < 8; ++i) {
        uint ai = (A.u[i >> 1] >> ((i & 1) << 4)) & 0xFFFF;
        uint bi = (B.u[i >> 1] >> ((i & 1) << 4)) & 0xFFFF;
        vt[((c7 << 3) + i) * 36 + Wp] = ai | (bi << 16);
      }
    }
    __syncthreads();

    unsigned long long wv[4];
#pragma unroll
    for (int r = 0; r < 4; ++r)
      wv[r] = SMASK[(size_t)(t0 + (w << 4) + (quad << 2) + r) * 16 + tile];

#pragma unroll
    for (int st = 0; st < 4; ++st) {
      f32x4 sacc = (f32x4){0.f, 0.f, 0.f, 0.f};
      const int srow = (st << 4) + l15;
      FragU kf0, kf1;
      kf0.u4 = *(const uint4*)(ks + srow * 36 + (quad << 2));
      kf1.u4 = *(const uint4*)(ks + srow * 36 + 16 + (quad << 2));
      sacc = __builtin_amdgcn_mfma_f32_16x16x32_bf16(qf0.f, kf0.f, sacc, 0, 0, 0);
      sacc = __builtin_amdgcn_mfma_f32_16x16x32_bf16(qf1.f, kf1.f, sacc, 0, 0, 0);

#pragma unroll
      for (int r = 0; r < 4; ++r) {
        const int trow = (quad << 2) + r;
        const uint bit = (uint)(wv[r] >> ((st << 4) + l15)) & 1u;
        const float val = bit ? __expf(sacc[r]) : 0.f;
        den[r] += val;
        const int W  = (st << 3) + (l15 >> 1);
        const int Wp = (W + (((trow >> 3) & 1) << 3)) & 31;
        ushort* p16 = (ushort*)(psw + trow * 36 + Wp);
        p16[l15 & 1] = f2bf(val);
      }
    }
#pragma unroll
    for (int ch = 0; ch < 2; ++ch) {
      FragU pf;
      const int pw = ((ch << 4) + (quad << 2) + (((l15 >> 3) & 1) << 3)) & 31;
      pf.u4 = *(const uint4*)(psw + l15 * 36 + pw);
#pragma unroll
      for (int nt = 0; nt < 4; ++nt) {
        const int d = (nt << 4) + l15;
        const int vw = ((ch << 4) + (quad << 2) + (((d >> 3) & 3) << 2)) & 31;
        FragU vf;
        vf.u4 = *(const uint4*)(vt + d * 36 + vw);
        oacc[nt] = __builtin_amdgcn_mfma_f32_16x16x32_bf16(pf.f, vf.f, oacc[nt], 0, 0, 0);
      }
    }
  }

#pragma unroll
  for (int r = 0; r < 4; ++r) {
    float d = den[r];
    d += __shfl_xor(d, 1);
    d += __shfl_xor(d, 2);
    d += __shfl_xor(d, 4);
    d += __shfl_xor(d, 8);
    den[r] = kT1 / d;
  }
  const int b = bh >> 3, h = bh & 7;
#pragma unroll
  for (int nt = 0; nt < 4; ++nt) {
#pragma unroll
    for (int r = 0; r < 4; ++r) {
      const int t = t0 + (w << 4) + (quad << 2) + r;
      const int d = (nt << 4) + l15;
      MIX16[(size_t)(t * kBsz + b) * kEmb + (h << 6) + d] =
          f2bf(oacc[nt][r] * den[r]);
    }
  }
}

// ---------------------------------------------------------------------------
// SSA single-pass: bf16 MFMA screen with running cross-lane max; candidates
// within margin recorded to per-wave list (superset-correct); survivors get
// the exact fp32 dot in R1's order; per-row resolve via 64-bit atomicMax.
// Block: 512 threads (8 waves, 128 t-rows).  Grid (8, 64).
// ---------------------------------------------------------------------------
__global__ __launch_bounds__(512, 2) void ssa_v3(
    const ushort* __restrict__ Q16, const ushort* __restrict__ K16,
    const float* __restrict__ Qf, const float* __restrict__ Kf,
    const ushort* __restrict__ V16,
    const unsigned long long* __restrict__ SMASK,
    ushort* __restrict__ MIX16)
{
  __shared__ uint ks[64 * 36];
  __shared__ uint2 list[8][kCap];
  __shared__ float thrL[8][16];
  __shared__ unsigned long long key64L[8][16];
  __shared__ uint cnt[8];

  const int t0  = blockIdx.x << 7;
  const int bh  = blockIdx.y;
  const int tid = threadIdx.x;
  const int w    = tid >> 6;
  const int l    = tid & 63;
  const int l15  = l & 15;
  const int quad = l >> 4;

  if (tid < 8) cnt[tid] = 0;
  if (tid < 128) ((unsigned long long*)key64L)[tid] = 0ull;

  const uint* Qu = (const uint*)Q16 + (size_t)bh * (kSeq * 32);
  const uint* Ku = (const uint*)K16 + (size_t)bh * (kSeq * 32);

  FragU qf0, qf1;
  {
    const uint* qrow = Qu + (size_t)(t0 + (w << 4) + l15) * 32;
    qf0.u4 = *(const uint4*)(qrow + (quad << 2));
    qf1.u4 = *(const uint4*)(qrow + 16 + (quad << 2));
  }

  float m4[4] = {-FLT_MAX, -FLT_MAX, -FLT_MAX, -FLT_MAX};

  for (int s0 = 0, tile = 0; s0 < kSeq; s0 += 64, ++tile) {
    __syncthreads();
    {   // stage K16 tile: 512 threads x 16 B
      const int row = tid >> 3, c = tid & 7;
      uint4 a = *(const uint4*)(Ku + (size_t)(s0 + row) * 32 + (c << 2));
      *(uint4*)(ks + row * 36 + (c << 2)) = a;
    }
    __syncthreads();

    unsigned long long wv[4];
#pragma unroll
    for (int r = 0; r < 4; ++r)
      wv[r] = SMASK[(size_t)(t0 + (w << 4) + (quad << 2) + r) * 16 + tile];

    f32x4 sv[4];
#pragma unroll
    for (int st = 0; st < 4; ++st) {
      f32x4 sacc = (f32x4){0.f, 0.f, 0.f, 0.f};
      const int srow = (st << 4) + l15;
      FragU kf0, kf1;
      kf0.u4 = *(const uint4*)(ks + srow * 36 + (quad << 2));
      kf1.u4 = *(const uint4*)(ks + srow * 36 + 16 + (quad << 2));
      sacc = __builtin_amdgcn_mfma_f32_16x16x32_bf16(qf0.f, kf0.f, sacc, 0, 0, 0);
      sacc = __builtin_amdgcn_mfma_f32_16x16x32_bf16(qf1.f, kf1.f, sacc, 0, 0, 0);
      sv[st] = sacc;
#pragma unroll
      for (int r = 0; r < 4; ++r) {
        const uint bit = (uint)(wv[r] >> ((st << 4) + l15)) & 1u;
        if (bit) m4[r] = fmaxf(m4[r], sacc[r]);
      }
    }
    // cross-lane running max (16 lanes per row share lane bits 0..3)
#pragma unroll
    for (int r = 0; r < 4; ++r) {
      float m = m4[r];
      m = fmaxf(m, __shfl_xor(m, 1));
      m = fmaxf(m, __shfl_xor(m, 2));
      m = fmaxf(m, __shfl_xor(m, 4));
      m = fmaxf(m, __shfl_xor(m, 8));
      m4[r] = m;
    }
    // record candidates vs tightened running threshold (superset of final)
#pragma unroll
    for (int st = 0; st < 4; ++st) {
#pragma unroll
      for (int r = 0; r < 4; ++r) {
        const uint bit = (uint)(wv[r] >> ((st << 4) + l15)) & 1u;
        const float x = sv[st][r];
        if (bit && x >= m4[r] - kMargin) {
          uint idx = atomicAdd(&cnt[w], 1u);
          if (idx < (uint)kCap) {
            const int rowid = (quad << 2) + r;
            const int s = s0 + (st << 4) + l15;
            list[w][idx] = make_uint2(__float_as_uint(x),
                                      ((uint)rowid << 10) | (uint)s);
          }
        }
      }
    }
  }

  // final thresholds to LDS
  if (l15 == 0) {
#pragma unroll
    for (int r = 0; r < 4; ++r) thrL[w][(quad << 2) + r] = m4[r] - kMargin;
  }
  __syncthreads();

  // verify survivors with the EXACT R1-order fp32 dot
  const uint n = min(cnt[w], (uint)kCap);
  const float* Qbf = Qf + (size_t)bh * (kSeq * kHD);
  const float* Kbf = Kf + (size_t)bh * (kSeq * kHD);
  for (uint base = 0; base < n; base += 64) {
    const uint e = base + (uint)l;
    if (e < n) {
      const uint2 ent = list[w][e];
      const uint rowid = ent.y >> 10;
      const uint s = ent.y & 1023u;
      const float xv = __uint_as_float(ent.x);
      if (xv >= thrL[w][rowid]) {
        const int t = t0 + (w << 4) + (int)rowid;
        const float* qe = Qbf + (size_t)t * kHD;
        const float* ke = Kbf + (size_t)s * kHD;
        float p0 = 0.f, p1 = 0.f, p2 = 0.f, p3 = 0.f;
#pragma unroll
        for (int i = 0; i < 16; ++i) {
          float4 qq = *(const float4*)(qe + (i << 2));
          float4 kk = *(const float4*)(ke + (i << 2));
          p0 = fmaf(qq.x, kk.x, p0);
          p1 = fmaf(qq.y, kk.y, p1);
          p2 = fmaf(qq.z, kk.z, p2);
          p3 = fmaf(qq.w, kk.w, p3);
        }
        const float acc = ((p0 + p1) + (p2 + p3)) * kScale;
        const unsigned long long key =
            ((unsigned long long)monokey(acc) << 16) |
            (unsigned long long)(1023u - s);
        atomicMax(&key64L[w][rowid], key);
      }
    }
  }
  __syncthreads();

  // gather v16[argmax] into MIX16
  const int b = bh >> 3, h = bh & 7;
  const uint* Vu = (const uint*)V16 + (size_t)bh * (kSeq * 32);
#pragma unroll
  for (int r = 0; r < 4; ++r) {
    const int rowid = (quad << 2) + r;
    const unsigned long long key = key64L[w][rowid];
    const uint s = 1023u - (uint)(key & 0xFFFFull);
    const uint2 vv = *(const uint2*)(Vu + (size_t)s * 32 + (l15 << 1));
    const int t = t0 + (w << 4) + rowid;
    uint* op = (uint*)MIX16 + ((size_t)(t * kBsz + b) * kEmb + (h << 6)) / 2 + (l15 << 1);
    uint2 o = *(uint2*)op;
    float o0 = bf2f(o.x & 0xFFFF) + kT2 * bf2f(vv.x & 0xFFFF);
    float o1 = bf2f(o.x >> 16)    + kT2 * bf2f(vv.x >> 16);
    float o2 = bf2f(o.y & 0xFFFF) + kT2 * bf2f(vv.y & 0xFFFF);
    float o3 = bf2f(o.y >> 16)    + kT2 * bf2f(vv.y >> 16);
    *(uint2*)op = make_uint2(pack2(o0, o1), pack2(o2, o3));
  }
}

extern "C" void kernel_launch(void* const* d_in, const int* in_sizes, int n_in,
                              void* d_out, int out_size, void* d_ws, size_t ws_size,
                              hipStream_t stream) {
  const float* query  = (const float*)d_in[0];
  const float* key    = (const float*)d_in[1];
  const float* value  = (const float*)d_in[2];
  const float* qsem   = (const float*)d_in[3];
  const float* ksem   = (const float*)d_in[4];
  const float* semmap = (const float*)d_in[5];
  const float* Wi     = (const float*)d_in[6];
  const float* bi     = (const float*)d_in[7];
  const float* Wo     = (const float*)d_in[8];
  const float* bo     = (const float*)d_in[9];
  float* out = (float*)d_out;

  char* ws = (char*)d_ws;
  unsigned long long* SMASK = (unsigned long long*)ws;          ws += 1024 * 16 * 8;
  ushort* Q16  = (ushort*)ws;  ws += (size_t)64 * kSeq * kHD * 2;   // 8 MB
  ushort* K16  = (ushort*)ws;  ws += (size_t)64 * kSeq * kHD * 2;   // 8 MB
  ushort* V16  = (ushort*)ws;  ws += (size_t)64 * kSeq * kHD * 2;   // 8 MB
  ushort* MIX16 = (ushort*)ws; ws += (size_t)kSeq * kBsz * kEmb * 2; // 8 MB
  float* P1 = (float*)ws;      ws += (size_t)64 * kSeq * kHD * 4;   // 16 MB
  float* P0 = out;   // d_out is dead until the final GEMM: use as fp32 Q proj

  const dim3 gp(64, 8);      // fp32 proj grid (128x64 tiles)
  const dim3 gb(64, 8);      // bf16 gemm grid (128x64 tiles)
  const dim3 gs(16, 64);     // sca: t-tile x bh
  const dim3 gv(8, 64);      // ssa: 128-row t-tile x bh

  smask_prep<<<1024, 256, 0, stream>>>(semmap, SMASK);
  // SCA projections (bf16 MFMA)
  gemm_bf16<<<gb, 256, 0, stream>>>(qsem, nullptr, Wi, bi, nullptr, Q16,
                                    0, 0, 1, kScale);
  gemm_bf16<<<gb, 256, 0, stream>>>(ksem, nullptr, Wi, bi, nullptr, K16,
                                    512, 0, 1, 1.0f);
  gemm_bf16<<<gb, 256, 0, stream>>>(value, nullptr, Wi, bi, nullptr, V16,
                                    1024, 0, 1, 1.0f);
  // SCA attention -> MIX16 = bf16(T1 * o_sca)
  sca_mfma2<<<gs, 256, 0, stream>>>(Q16, K16, V16, SMASK, MIX16);
  // SSA projections: fp32 math identical to R1 + bf16 shadows
  proj_v2<<<gp, 256, 0, stream>>>(query, Wi, bi, P0, 0,   Q16, kScale);
  proj_v2<<<gp, 256, 0, stream>>>(key,   Wi, bi, P1, 512, K16, 1.0f);
  // SSA screen+verify -> MIX16 += bf16(T2 * v[argmax])
  ssa_v3<<<gv, 512, 0, stream>>>(Q16, K16, P0, P1, V16, SMASK, MIX16);
  // Out projection (reads bf16 MIX16 directly)
  gemm_bf16<<<gb, 256, 0, stream>>>(nullptr, MIX16, Wo, bo, out, nullptr,
                                    0, 2, 0, 1.0f);
}